// Round 9
// baseline (191.638 us; speedup 1.0000x reference)
//
#include <hip/hip_runtime.h>
#include <cstddef>

#define CC 128
#define NH 8
#define HD 16
#define DDIM 31
#define HWW 1024
#define TOK 31744   // DDIM * HWW
#define SCALE2 0.0625f   // (HD^-0.5)^2 — both QK^T operands pre-scaled in the ref
#define QT2 32      // r21 projection token tile (grid 992 -> 4 blocks/CU)

typedef __attribute__((ext_vector_type(4))) short  short4v;
typedef __attribute__((ext_vector_type(8))) short  short8v;
typedef __attribute__((ext_vector_type(4))) float  float4v;
typedef __attribute__((ext_vector_type(2))) unsigned uint2v;
typedef __attribute__((ext_vector_type(8))) __bf16 bf16x8;

__device__ inline unsigned bf16rne(float f) {
    unsigned u = __float_as_uint(f);
    return (u + 0x7fffu + ((u >> 16) & 1u)) >> 16;
}
__device__ inline float bf2f(unsigned h) { return __uint_as_float(h << 16); }

// Packed activation element: dword = hi_bf16 | (lo_bf16 << 16).
__device__ inline unsigned packsplit(float v) {
    unsigned h = bf16rne(v);
    unsigned l = bf16rne(v - bf2f(h));
    return h | (l << 16);
}
__device__ inline uint2 pack_hi4(uint4 p) {
    return make_uint2((p.x & 0xffffu) | (p.y << 16),
                      (p.z & 0xffffu) | (p.w << 16));
}
__device__ inline uint2 pack_lo4(uint4 p) {
    return make_uint2((p.x >> 16) | (p.y & 0xffff0000u),
                      (p.z >> 16) | (p.w & 0xffff0000u));
}

// bf16-truncate pack of 4 exp'd scores via 2x v_perm_b32 (bit-identical
// to 4x (short)(u>>16); verified r15+, absmax unchanged).
__device__ inline short4v pack_pf(unsigned u0, unsigned u1,
                                  unsigned u2, unsigned u3) {
    uint2v pd;
    pd[0] = __builtin_amdgcn_perm(u1, u0, 0x07060302u);  // [u0.hi16 | u1.hi16<<16]
    pd[1] = __builtin_amdgcn_perm(u3, u2, 0x07060302u);
    return __builtin_bit_cast(short4v, pd);
}

// Native gfx950 16x16x32 bf16 MFMA (projections, K=128). A/B built with the
// SAME per-lane k-mapping — contraction-sum-immune; C/D layout identical to
// 16x16x16 (row=quad*4+reg, col=l).
__device__ inline float4v mfma32(short8v a, short8v b, float4v c) {
    return __builtin_amdgcn_mfma_f32_16x16x32_bf16(
        __builtin_bit_cast(bf16x8, a), __builtin_bit_cast(bf16x8, b), c, 0, 0, 0);
}

#define AST 136   // LDS act row stride (ushorts); 136 -> ds_read_b128 16B-aligned

// ---------------------------------------------------------------------------
// Kernel 1 (r21): Q projection, BOTH branches, 32-token tiles, 256 threads,
// grid 992, LB(256,4) -> 4 blocks/CU (was 2). Theory: projections are
// latency-bound (each ~56 µs vs ~10 µs roofline; all instruction-count
// reductions were null; the single prior win was 1->2 blocks/CU). More
// resident blocks overlap each other's stage/compute/store latency gaps.
// Each wave covers co-halves {wv*16, wv*16+64}; weights converted per-k4
// in-loop (register-light, ~80 VGPR < 128 cap).
// ---------------------------------------------------------------------------
__global__ __launch_bounds__(256, 4) void qproj_kernel(
    const float* __restrict__ x,
    const float* __restrict__ Wq1, const float* __restrict__ Wq2,
    const float* __restrict__ bq1, const float* __restrict__ bq2,
    unsigned* __restrict__ q1p, unsigned* __restrict__ q2p,
    float* __restrict__ sums)
{
    __shared__ ushort sbuf[2 * QT2 * AST];   // 17.4 KB: x hi/lo, then out staging
    ushort* Ahi = sbuf;
    ushort* Alo = sbuf + QT2 * AST;
    unsigned* S = (unsigned*)sbuf;           // 32 x 136 dwords (exact fit)
    const int tid = threadIdx.x;
    const int t0  = blockIdx.x * QT2;
    if (blockIdx.x == 0) sums[tid] = 0.f;    // 256 threads == 2*CC exactly

    // stage x tile transposed + split: [t][ci] (coalesced token-major reads)
#pragma unroll
    for (int i = tid; i < QT2 * 32; i += 256) {
        int t = i & 31, c4 = i >> 5;
        unsigned hw[2], lw[2];
#pragma unroll
        for (int p = 0; p < 2; ++p) {
            unsigned h0, l0, h1, l1;
            {
                float v = x[(size_t)(c4 * 4 + p * 2 + 0) * TOK + t0 + t];
                h0 = bf16rne(v); l0 = bf16rne(v - bf2f(h0));
            }
            {
                float v = x[(size_t)(c4 * 4 + p * 2 + 1) * TOK + t0 + t];
                h1 = bf16rne(v); l1 = bf16rne(v - bf2f(h1));
            }
            hw[p] = h0 | (h1 << 16);
            lw[p] = l0 | (l1 << 16);
        }
        *(uint2*)&Ahi[t * AST + c4 * 4] = make_uint2(hw[0], hw[1]);
        *(uint2*)&Alo[t * AST + c4 * 4] = make_uint2(lw[0], lw[1]);
    }
    __syncthreads();

    const int lane = tid & 63;
    const int l    = lane & 15;
    const int quad = lane >> 4;
    const int wv   = tid >> 6;               // 0..3

    float4v acc[2][2][2];                    // [branch][co-half][nt]
#pragma unroll
    for (int br = 0; br < 2; ++br)
#pragma unroll
        for (int hf = 0; hf < 2; ++hf)
#pragma unroll
            for (int nt = 0; nt < 2; ++nt)
                acc[br][hf][nt] = (float4v){0.f, 0.f, 0.f, 0.f};

#pragma unroll
    for (int hf = 0; hf < 2; ++hf) {
        const int co0 = wv * 16 + hf * 64;
#pragma unroll
        for (int k4 = 0; k4 < 4; ++k4) {
            short8v ah0, al0, ah1, al1;
#pragma unroll
            for (int j = 0; j < 8; ++j) {
                float w1 = Wq1[(size_t)(k4 * 32 + quad * 8 + j) * CC + co0 + l];
                unsigned h1 = bf16rne(w1);
                ah0[j] = (short)h1; al0[j] = (short)bf16rne(w1 - bf2f(h1));
                float w2 = Wq2[(size_t)(k4 * 32 + quad * 8 + j) * CC + co0 + l];
                unsigned h2 = bf16rne(w2);
                ah1[j] = (short)h2; al1[j] = (short)bf16rne(w2 - bf2f(h2));
            }
#pragma unroll
            for (int nt = 0; nt < 2; ++nt) {
                short8v bh = *(const short8v*)&Ahi[(nt * 16 + l) * AST + k4 * 32 + quad * 8];
                short8v bl = *(const short8v*)&Alo[(nt * 16 + l) * AST + k4 * 32 + quad * 8];
                acc[0][hf][nt] = mfma32(ah0, bh, acc[0][hf][nt]);
                acc[0][hf][nt] = mfma32(ah0, bl, acc[0][hf][nt]);
                acc[0][hf][nt] = mfma32(al0, bh, acc[0][hf][nt]);
                acc[1][hf][nt] = mfma32(ah1, bh, acc[1][hf][nt]);
                acc[1][hf][nt] = mfma32(ah1, bl, acc[1][hf][nt]);
                acc[1][hf][nt] = mfma32(al1, bh, acc[1][hf][nt]);
            }
        }
    }

    // staged epilogues: LDS tile then contiguous full-line stores
    for (int branch = 0; branch < 2; ++branch) {
        const float* bq = branch ? bq2 : bq1;
        unsigned* op    = branch ? q2p : q1p;
        __syncthreads();   // previous use of sbuf done
#pragma unroll
        for (int hf = 0; hf < 2; ++hf) {
            const int co0 = wv * 16 + hf * 64;
            float4 bv = *(const float4*)&bq[co0 + quad * 4];
            float bb[4] = {bv.x, bv.y, bv.z, bv.w};
#pragma unroll
            for (int nt = 0; nt < 2; ++nt)
#pragma unroll
                for (int reg = 0; reg < 4; ++reg)
                    S[(nt * 16 + l) * AST + co0 + quad * 4 + reg] =
                        packsplit(acc[branch][hf][nt][reg] + bb[reg]);
        }
        __syncthreads();
#pragma unroll
        for (int i = tid; i < QT2 * 32; i += 256) {
            int t = i >> 5, c4 = i & 31;
            uint4 pv = *(const uint4*)&S[t * AST + c4 * 4];
            *(uint4*)&op[(size_t)(t0 + t) * CC + c4 * 4] = pv;   // 512 B/32 lanes
        }
    }
}

// ---------------------------------------------------------------------------
// Kernel 2: FUSED attention, grid 248 — r16 body verbatim (59.4 µs, stable
// across 4 containers). Phase 1 spatial: O^T = V^T·P^T in-place on q2p;
// rowsums via ones-MFMA. Phase 2: spectral jobs.
// ---------------------------------------------------------------------------
#define QS2 132
#define QSS 20
#define QTP 1044
__global__ __launch_bounds__(1024, 4) void attn_kernel(
    unsigned* __restrict__ q1p, unsigned* __restrict__ q2p,
    float* __restrict__ sums)
{
    __shared__ __align__(16) ushort smem[HWW * QSS + HD * QTP];  // 74.4 KB
    __shared__ float fsum[CC];
    const int tid  = threadIdx.x;
    const int lane = tid & 63;
    const int l    = lane & 15;
    const int quad = lane >> 4;
    const float k2 = SCALE2 * 1.44269504f;
    const short4v onesb = {(short)0x3F80, (short)0x3F80, (short)0x3F80, (short)0x3F80};
    if (tid < CC) fsum[tid] = 0.f;

    // ---------------- phase 1: spatial slice (O^T form) ----------------
    {
        const int d = blockIdx.x >> 3, h = blockIdx.x & 7;
        ushort* Qs  = smem;
        ushort* QTs = smem + HWW * QSS;
        const size_t base = (size_t)d * HWW * CC + h * HD;   // dword index

        for (int i = tid; i < HWW * 4; i += 1024) {
            int row = i >> 2, q4 = i & 3;
            uint4 p = *(const uint4*)&q2p[base + (size_t)row * CC + q4 * 4];
            *(uint2*)&Qs[row * QSS + q4 * 4] = pack_hi4(p);
            QTs[(q4 * 4 + 0) * QTP + row] = (ushort)p.x;
            QTs[(q4 * 4 + 1) * QTP + row] = (ushort)p.y;
            QTs[(q4 * 4 + 2) * QTP + row] = (ushort)p.z;
            QTs[(q4 * 4 + 3) * QTP + row] = (ushort)p.w;
        }
        __syncthreads();

        const int Rw = (tid >> 6) * 64;
        short4v qf[4];
#pragma unroll
        for (int lt = 0; lt < 4; ++lt) {
            short4v raw = *(short4v*)&Qs[(Rw + lt * 16 + l) * QSS + quad * 4];
            short4v sc;
#pragma unroll
            for (int e = 0; e < 4; ++e) {
                float f = bf2f((unsigned)(ushort)raw[e]) * k2;
                sc[e] = (short)bf16rne(f);
            }
            qf[lt] = sc;
        }

        float4v acc[4], accs[4];
#pragma unroll
        for (int lt = 0; lt < 4; ++lt) {
            acc[lt]  = (float4v){0.f, 0.f, 0.f, 0.f};
            accs[lt] = (float4v){0.f, 0.f, 0.f, 0.f};
        }

#pragma unroll 2
        for (int mt = 0; mt < 64; ++mt) {
            const int m0 = mt * 16;
            short4v ka = *(short4v*)&Qs[(m0 + l) * QSS + quad * 4];
            short4v vb = *(short4v*)&QTs[l * QTP + m0 + quad * 4];   // V^T A-frag
#pragma unroll
            for (int lt = 0; lt < 4; ++lt) {
                float4v s = __builtin_amdgcn_mfma_f32_16x16x16bf16_1k(
                    ka, qf[lt], (float4v){0.f, 0.f, 0.f, 0.f}, 0, 0, 0);
                unsigned u0 = __float_as_uint(__builtin_amdgcn_exp2f(s[0]));
                unsigned u1 = __float_as_uint(__builtin_amdgcn_exp2f(s[1]));
                unsigned u2 = __float_as_uint(__builtin_amdgcn_exp2f(s[2]));
                unsigned u3 = __float_as_uint(__builtin_amdgcn_exp2f(s[3]));
                short4v pf = pack_pf(u0, u1, u2, u3);
                // O^T[channel][query] += V^T · P^T ; denom via A=ones
                acc[lt]  = __builtin_amdgcn_mfma_f32_16x16x16bf16_1k(vb, pf, acc[lt], 0, 0, 0);
                accs[lt] = __builtin_amdgcn_mfma_f32_16x16x16bf16_1k(onesb, pf, accs[lt], 0, 0, 0);
            }
        }

        float vsum[4] = {0.f, 0.f, 0.f, 0.f};
#pragma unroll
        for (int lt = 0; lt < 4; ++lt) {
            float inv = 1.f / accs[lt][0];   // denom(query = Rw+lt*16+l); rows equal
            int token = Rw + lt * 16 + l;
            float v0 = acc[lt][0] * inv, v1 = acc[lt][1] * inv;
            float v2 = acc[lt][2] * inv, v3 = acc[lt][3] * inv;
            uint4 pv;
            pv.x = packsplit(v0); pv.y = packsplit(v1);
            pv.z = packsplit(v2); pv.w = packsplit(v3);
            *(uint4*)&q2p[base + (size_t)token * CC + quad * 4] = pv;
            vsum[0] += v0; vsum[1] += v1; vsum[2] += v2; vsum[3] += v3;
        }
#pragma unroll
        for (int reg = 0; reg < 4; ++reg) {
            float v = vsum[reg];
            v += __shfl_xor(v, 1); v += __shfl_xor(v, 2);
            v += __shfl_xor(v, 4); v += __shfl_xor(v, 8);
            if (l == 0) atomicAdd(&fsum[quad * 4 + reg], v);
        }
        __syncthreads();
        if (tid < HD) atomicAdd(&sums[CC + h * HD + tid], fsum[tid]);
    }

    // ---------------- phase 2: spectral job (if assigned) ----------------
    const int half_id = blockIdx.x >> 1;
    const bool has_job = (blockIdx.x & 1) ? (half_id < 4) : (half_id < 124);
    if (!has_job) return;
    const int job = (blockIdx.x & 1) ? (124 + half_id) : half_id;
    const int hw0 = job * 8;

    __syncthreads();                       // phase-1 smem reads + fsum use done
    if (tid < CC) fsum[tid] = 0.f;

    const int wave = tid >> 6;
    const int hwl  = wave >> 1;
    const int half = wave & 1;
    const int hw   = hw0 + hwl;
    ushort* Q = smem + hwl * (32 * QS2);
    for (int it = 0; it < 8; ++it) {
        int idx = it * 64 + lane;
        int dd = half * 16 + (idx >> 5), c4 = idx & 31;
        if (dd < 31) {
            uint4 p = *(const uint4*)&q1p[((size_t)dd * HWW + hw) * CC + c4 * 4];
            *(uint2*)&Q[dd * QS2 + c4 * 4] = pack_hi4(p);
        }
    }
    if (half) for (int i = lane; i < 128; i += 64) Q[31 * QS2 + i] = 0;
    __syncthreads();

    const int hh = half * 4;
#pragma unroll
    for (int hl = 0; hl < 4; ++hl) {
        const int hc = (hh + hl) * HD;
        short4v qf[2];
        qf[0] = *(const short4v*)&Q[l * QS2 + hc + quad * 4];
        qf[1] = *(const short4v*)&Q[(16 + l) * QS2 + hc + quad * 4];
        short4v va[2];
#pragma unroll
        for (int j = 0; j < 2; ++j)
#pragma unroll
            for (int jj = 0; jj < 4; ++jj)
                va[j][jj] = (short)Q[(j * 16 + quad * 4 + jj) * QS2 + hc + l];

        float4v o[2]   = {(float4v){0.f,0.f,0.f,0.f}, (float4v){0.f,0.f,0.f,0.f}};
        float4v osr[2] = {(float4v){0.f,0.f,0.f,0.f}, (float4v){0.f,0.f,0.f,0.f}};
#pragma unroll
        for (int j = 0; j < 2; ++j) {
#pragma unroll
            for (int i2 = 0; i2 < 2; ++i2) {
                float4v s = __builtin_amdgcn_mfma_f32_16x16x16bf16_1k(
                    qf[j], qf[i2], (float4v){0.f,0.f,0.f,0.f}, 0, 0, 0);
                unsigned u0 = __float_as_uint(__builtin_amdgcn_exp2f(s[0] * k2));
                unsigned u1 = __float_as_uint(__builtin_amdgcn_exp2f(s[1] * k2));
                unsigned u2 = __float_as_uint(__builtin_amdgcn_exp2f(s[2] * k2));
                unsigned u3 = __float_as_uint(__builtin_amdgcn_exp2f(s[3] * k2));
                if (j == 1 && quad == 3) u3 = 0;   // mask key 31
                short4v pf = pack_pf(u0, u1, u2, u3);
                o[i2]   = __builtin_amdgcn_mfma_f32_16x16x16bf16_1k(va[j], pf, o[i2], 0, 0, 0);
                osr[i2] = __builtin_amdgcn_mfma_f32_16x16x16bf16_1k(onesb, pf, osr[i2], 0, 0, 0);
            }
        }
        float vsum[4] = {0.f, 0.f, 0.f, 0.f};
#pragma unroll
        for (int i2 = 0; i2 < 2; ++i2) {
            float inv = 1.f / osr[i2][0];   // rowsum(query=i2*16+l), this lane
            int dq = i2 * 16 + l;
            if (dq < 31) {
                uint4 pv;
                float v0 = o[i2][0] * inv, v1 = o[i2][1] * inv;
                float v2 = o[i2][2] * inv, v3 = o[i2][3] * inv;
                pv.x = packsplit(v0); pv.y = packsplit(v1);
                pv.z = packsplit(v2); pv.w = packsplit(v3);
                *(uint4*)&q1p[((size_t)dq * HWW + hw) * CC + hc + quad * 4] = pv;
                vsum[0] += v0; vsum[1] += v1; vsum[2] += v2; vsum[3] += v3;
            }
        }
#pragma unroll
        for (int r = 0; r < 4; ++r) {
            float v = vsum[r];
            v += __shfl_xor(v, 1); v += __shfl_xor(v, 2);
            v += __shfl_xor(v, 4); v += __shfl_xor(v, 8);
            if (l == 0) atomicAdd(&fsum[hc + quad * 4 + r], v);
        }
    }
    __syncthreads();
    if (tid < CC) atomicAdd(&sums[tid], fsum[tid]);
}

// ---------------------------------------------------------------------------
// Kernel 2.5: gate computed ONCE (r18 body, proven correct) — keeps the
// GEMV out of all 992 oproj blocks. Exact reference math, f32.
// ---------------------------------------------------------------------------
__global__ __launch_bounds__(512) void gate_kernel(
    const float* __restrict__ Wp1, const float* __restrict__ Wp2,
    const float* __restrict__ bp1, const float* __restrict__ bp2,
    const float* __restrict__ Wg,  const float* __restrict__ bg,
    const float* __restrict__ sums, float* __restrict__ gfp)
{
    __shared__ float pa[4][CC];
    __shared__ float giv[2 * CC];
    const int tid = threadIdx.x;
    const int part = tid >> 7, c = tid & 127;
    const float* Wp = (part < 2) ? Wp1 : Wp2;
    const float* sp = (part < 2) ? sums : sums + CC;
    const int k0 = (part & 1) * 64;
    float a = 0.f;
    for (int kk = 0; kk < 64; ++kk) {
        int k = k0 + kk;
        a += sp[k] * Wp[(size_t)k * CC + c];
    }
    pa[part][c] = a;
    __syncthreads();
    if (tid < 2 * CC) {
        float m = (tid < CC) ? (pa[0][tid] + pa[1][tid])
                             : (pa[2][tid - CC] + pa[3][tid - CC]);
        float bb = (tid < CC) ? bp1[tid] : bp2[tid - CC];
        giv[tid] = m * (1.f / (float)TOK) + bb;
    }
    __syncthreads();
    float b = 0.f;
    for (int kk = 0; kk < 64; ++kk) {
        int j = part * 64 + kk;
        b += giv[j] * Wg[(size_t)j * CC + c];
    }
    pa[part][c] = b;
    __syncthreads();
    if (tid < CC)
        gfp[tid] = 1.f / (1.f + __expf(-(bg[tid] + pa[0][tid] + pa[1][tid] +
                                        pa[2][tid] + pa[3][tid])));
}

// ---------------------------------------------------------------------------
// Kernel 3 (r21): output projection, BOTH branches, 32-token tiles, 256
// threads, grid 992, LB(256,4) -> 4 blocks/CU. Gate read from gfp.
// ---------------------------------------------------------------------------
__global__ __launch_bounds__(256, 4) void oproj_kernel(
    const unsigned* __restrict__ q1p, const unsigned* __restrict__ q2p,
    const float* __restrict__ Wp1, const float* __restrict__ Wp2,
    const float* __restrict__ bp1, const float* __restrict__ bp2,
    const float* __restrict__ gfp, float* __restrict__ out)
{
    __shared__ ushort sbuf[2 * QT2 * AST];   // 17.4 KB: act hi/lo, then out staging
    ushort* Ahi = sbuf;
    ushort* Alo = sbuf + QT2 * AST;
    unsigned* S = (unsigned*)sbuf;           // 128 co x 34 dwords (4352, exact fit)
    const int tid = threadIdx.x;
    const int t0  = blockIdx.x * QT2;
    const int lane = tid & 63;
    const int l    = lane & 15;
    const int quad = lane >> 4;
    const int wv   = tid >> 6;               // 0..3

    float4v acc[2][2][2];                    // [branch][co-half][nt]
#pragma unroll
    for (int br = 0; br < 2; ++br)
#pragma unroll
        for (int hf = 0; hf < 2; ++hf)
#pragma unroll
            for (int nt = 0; nt < 2; ++nt)
                acc[br][hf][nt] = (float4v){0.f, 0.f, 0.f, 0.f};

    for (int br = 0; br < 2; ++br) {
        const unsigned* Ap = br ? q2p : q1p;
        const float*    W  = br ? Wp2 : Wp1;
        if (br) __syncthreads();   // previous branch LDS reads done
#pragma unroll
        for (int i = tid; i < QT2 * 32; i += 256) {
            int t = i >> 5, c4 = i & 31;
            uint4 p = *(const uint4*)&Ap[(size_t)(t0 + t) * CC + c4 * 4];
            *(uint2*)&Ahi[t * AST + c4 * 4] = pack_hi4(p);
            *(uint2*)&Alo[t * AST + c4 * 4] = pack_lo4(p);
        }
        __syncthreads();
#pragma unroll
        for (int hf = 0; hf < 2; ++hf) {
            const int co0 = wv * 16 + hf * 64;
#pragma unroll
            for (int k4 = 0; k4 < 4; ++k4) {
                short8v ah, al;
#pragma unroll
                for (int j = 0; j < 8; ++j) {
                    float w = W[(size_t)(k4 * 32 + quad * 8 + j) * CC + co0 + l];
                    unsigned h = bf16rne(w);
                    ah[j] = (short)h; al[j] = (short)bf16rne(w - bf2f(h));
                }
#pragma unroll
                for (int nt = 0; nt < 2; ++nt) {
                    short8v bh = *(const short8v*)&Ahi[(nt * 16 + l) * AST + k4 * 32 + quad * 8];
                    short8v bl = *(const short8v*)&Alo[(nt * 16 + l) * AST + k4 * 32 + quad * 8];
                    acc[br][hf][nt] = mfma32(ah, bh, acc[br][hf][nt]);
                    acc[br][hf][nt] = mfma32(ah, bl, acc[br][hf][nt]);
                    acc[br][hf][nt] = mfma32(al, bh, acc[br][hf][nt]);
                }
            }
        }
    }

    // staged epilogue: [co][t] tile in LDS (stride 34), then contiguous stores
    __syncthreads();   // act LDS reads done
#pragma unroll
    for (int hf = 0; hf < 2; ++hf) {
        const int co0 = wv * 16 + hf * 64;
        float4 b1 = *(const float4*)&bp1[co0 + quad * 4];
        float4 b2 = *(const float4*)&bp2[co0 + quad * 4];
        float4 gv = *(const float4*)&gfp[co0 + quad * 4];
        float bb1[4] = {b1.x, b1.y, b1.z, b1.w};
        float bb2[4] = {b2.x, b2.y, b2.z, b2.w};
        float gg[4]  = {gv.x, gv.y, gv.z, gv.w};
#pragma unroll
        for (int nt = 0; nt < 2; ++nt) {
            int tl = nt * 16 + l;
#pragma unroll
            for (int reg = 0; reg < 4; ++reg) {
                float v = gg[reg] * (acc[0][hf][nt][reg] + bb1[reg]) +
                          (1.f - gg[reg]) * (acc[1][hf][nt][reg] + bb2[reg]);
                S[(co0 + quad * 4 + reg) * 34 + tl] = __float_as_uint(v);
            }
        }
    }
    __syncthreads();
#pragma unroll
    for (int i = tid; i < 128 * 16; i += 256) {
        int co = i >> 4, t2 = i & 15;
        uint2 v = *(const uint2*)&S[co * 34 + t2 * 2];
        *(uint2*)&out[(size_t)co * TOK + t0 + t2 * 2] = v;
    }
}

extern "C" void kernel_launch(void* const* d_in, const int* in_sizes, int n_in,
                              void* d_out, int out_size, void* d_ws, size_t ws_size,
                              hipStream_t stream)
{
    const float* x   = (const float*)d_in[0];
    const float* Wq1 = (const float*)d_in[1];
    const float* bq1 = (const float*)d_in[2];
    const float* Wp1 = (const float*)d_in[3];
    const float* bp1 = (const float*)d_in[4];
    const float* Wq2 = (const float*)d_in[5];
    const float* bq2 = (const float*)d_in[6];
    const float* Wp2 = (const float*)d_in[7];
    const float* bp2 = (const float*)d_in[8];
    const float* Wg  = (const float*)d_in[9];
    const float* bg  = (const float*)d_in[10];
    float* out = (float*)d_out;

    const size_t plane = (size_t)TOK * CC;             // dwords per packed plane
    unsigned* q1p = (unsigned*)d_ws;
    unsigned* q2p = q1p + plane;
    float*   sums = (float*)(q2p + plane);             // 256 floats (zeroed by qproj)
    float*   gfp  = sums + 2 * CC;                     // 128 floats (gate)

    const size_t need = 2 * plane * sizeof(unsigned) + (2 * CC + CC) * sizeof(float);
    if (ws_size < need) return;

    qproj_kernel<<<dim3(TOK / QT2), 256, 0, stream>>>(x, Wq1, Wq2, bq1, bq2,
                                                      q1p, q2p, sums);
    attn_kernel<<<dim3(248), 1024, 0, stream>>>(q1p, q2p, sums);
    gate_kernel<<<dim3(1), 512, 0, stream>>>(Wp1, Wp2, bp1, bp2, Wg, bg,
                                             sums, gfp);
    oproj_kernel<<<dim3(TOK / QT2), 256, 0, stream>>>(q1p, q2p, Wp1, Wp2,
                                                      bp1, bp2, gfp, out);
}

// Round 10
// 178.483 us; speedup vs baseline: 1.0737x; 1.0737x over previous
//
#include <hip/hip_runtime.h>
#include <cstddef>

#define CC 128
#define NH 8
#define HD 16
#define DDIM 31
#define HWW 1024
#define TOK 31744   // DDIM * HWW
#define SCALE2 0.0625f   // (HD^-0.5)^2 — both QK^T operands pre-scaled in the ref
#define QTOK 64     // qproj token tile (grid 496 -> 2 blocks/CU)

typedef __attribute__((ext_vector_type(4))) short  short4v;
typedef __attribute__((ext_vector_type(8))) short  short8v;
typedef __attribute__((ext_vector_type(4))) float  float4v;
typedef __attribute__((ext_vector_type(2))) unsigned uint2v;
typedef __attribute__((ext_vector_type(8))) __bf16 bf16x8;

__device__ inline unsigned bf16rne(float f) {
    unsigned u = __float_as_uint(f);
    return (u + 0x7fffu + ((u >> 16) & 1u)) >> 16;
}
__device__ inline float bf2f(unsigned h) { return __uint_as_float(h << 16); }

// Packed activation element: dword = hi_bf16 | (lo_bf16 << 16).
__device__ inline unsigned packsplit(float v) {
    unsigned h = bf16rne(v);
    unsigned l = bf16rne(v - bf2f(h));
    return h | (l << 16);
}
__device__ inline uint2 pack_hi4(uint4 p) {
    return make_uint2((p.x & 0xffffu) | (p.y << 16),
                      (p.z & 0xffffu) | (p.w << 16));
}
__device__ inline uint2 pack_lo4(uint4 p) {
    return make_uint2((p.x >> 16) | (p.y & 0xffff0000u),
                      (p.z >> 16) | (p.w & 0xffff0000u));
}

// bf16-truncate pack of 4 exp'd scores via 2x v_perm_b32 (bit-identical
// to 4x (short)(u>>16); verified r15+, absmax unchanged).
__device__ inline short4v pack_pf(unsigned u0, unsigned u1,
                                  unsigned u2, unsigned u3) {
    uint2v pd;
    pd[0] = __builtin_amdgcn_perm(u1, u0, 0x07060302u);  // [u0.hi16 | u1.hi16<<16]
    pd[1] = __builtin_amdgcn_perm(u3, u2, 0x07060302u);
    return __builtin_bit_cast(short4v, pd);
}

// Native gfx950 16x16x32 bf16 MFMA (projections, K=128). A/B built with the
// SAME per-lane k-mapping — contraction-sum-immune; C/D layout identical to
// 16x16x16 (row=quad*4+reg, col=l).
__device__ inline float4v mfma32(short8v a, short8v b, float4v c) {
    return __builtin_amdgcn_mfma_f32_16x16x32_bf16(
        __builtin_bit_cast(bf16x8, a), __builtin_bit_cast(bf16x8, b), c, 0, 0, 0);
}

// Load a wave's W^T A-frags (16 co x 128 k) from global W[k][co] as FOUR
// K=32 fragments, split to bf16 hi/lo in-register. Weights L2/L3-hot.
__device__ inline void load_wfrags32(const float* __restrict__ W, int co0, int l,
                                     int quad, short8v* ah, short8v* al)
{
#pragma unroll
    for (int k4 = 0; k4 < 4; ++k4) {
#pragma unroll
        for (int j = 0; j < 8; ++j) {
            float w = W[(size_t)(k4 * 32 + quad * 8 + j) * CC + co0 + l];
            unsigned h = bf16rne(w);
            ah[k4][j] = (short)h;
            al[k4][j] = (short)bf16rne(w - bf2f(h));
        }
    }
}

#define AST 136   // LDS act row stride (ushorts); 136 -> ds_read_b128 16B-aligned

// ---------------------------------------------------------------------------
// Kernel 1: Q projection — r8 body verbatim (best measured config: 64-token
// tiles, grid 496, LB(512,4)). r21's 32-token/4-blk-CU variant regressed
// +20 µs (per-block fixed work dominates), reverted.
// ---------------------------------------------------------------------------
__global__ __launch_bounds__(512, 4) void qproj_kernel(
    const float* __restrict__ x,
    const float* __restrict__ Wq1, const float* __restrict__ Wq2,
    const float* __restrict__ bq1, const float* __restrict__ bq2,
    unsigned* __restrict__ q1p, unsigned* __restrict__ q2p,
    float* __restrict__ sums)
{
    __shared__ ushort sbuf[2 * QTOK * AST];   // 34.8 KB: x hi/lo, then out staging
    ushort* Ahi = sbuf;
    ushort* Alo = sbuf + QTOK * AST;
    unsigned* S = (unsigned*)sbuf;            // 64 x 136 dwords (exact fit)
    const int tid = threadIdx.x;
    const int t0  = blockIdx.x * QTOK;
    if (blockIdx.x == 0 && tid < 2 * CC) sums[tid] = 0.f;   // for attn's atomics

    // stage x tile transposed + split: [t][ci] (once, shared by both branches)
    for (int i = tid; i < QTOK * 32; i += 512) {
        int t = i & 63, c4 = i >> 6;          // lanes: consecutive t -> coalesced
        unsigned hw[2], lw[2];
#pragma unroll
        for (int p = 0; p < 2; ++p) {
            unsigned h0, l0, h1, l1;
            {
                float v = x[(size_t)(c4 * 4 + p * 2 + 0) * TOK + t0 + t];
                h0 = bf16rne(v); l0 = bf16rne(v - bf2f(h0));
            }
            {
                float v = x[(size_t)(c4 * 4 + p * 2 + 1) * TOK + t0 + t];
                h1 = bf16rne(v); l1 = bf16rne(v - bf2f(h1));
            }
            hw[p] = h0 | (h1 << 16);
            lw[p] = l0 | (l1 << 16);
        }
        *(uint2*)&Ahi[t * AST + c4 * 4] = make_uint2(hw[0], hw[1]);
        *(uint2*)&Alo[t * AST + c4 * 4] = make_uint2(lw[0], lw[1]);
    }
    __syncthreads();

    const int lane = tid & 63;
    const int l    = lane & 15;
    const int quad = lane >> 4;
    const int co0  = (tid >> 6) * 16;

    // weight frags for BOTH branches live; one shared pass over LDS B-frags
    short8v ah[2][4], al[2][4];
    load_wfrags32(Wq1, co0, l, quad, ah[0], al[0]);
    load_wfrags32(Wq2, co0, l, quad, ah[1], al[1]);
    float4v acc[2][4];
#pragma unroll
    for (int br = 0; br < 2; ++br)
#pragma unroll
        for (int nt = 0; nt < 4; ++nt) acc[br][nt] = (float4v){0.f, 0.f, 0.f, 0.f};
#pragma unroll
    for (int k4 = 0; k4 < 4; ++k4) {
#pragma unroll
        for (int nt = 0; nt < 4; ++nt) {
            short8v bh = *(const short8v*)&Ahi[(nt * 16 + l) * AST + k4 * 32 + quad * 8];
            short8v bl = *(const short8v*)&Alo[(nt * 16 + l) * AST + k4 * 32 + quad * 8];
            acc[0][nt] = mfma32(ah[0][k4], bh, acc[0][nt]);
            acc[0][nt] = mfma32(ah[0][k4], bl, acc[0][nt]);
            acc[0][nt] = mfma32(al[0][k4], bh, acc[0][nt]);
            acc[1][nt] = mfma32(ah[1][k4], bh, acc[1][nt]);
            acc[1][nt] = mfma32(ah[1][k4], bl, acc[1][nt]);
            acc[1][nt] = mfma32(al[1][k4], bh, acc[1][nt]);
        }
    }

    // staged epilogues: LDS tile then contiguous full-line stores
    for (int branch = 0; branch < 2; ++branch) {
        const float* bq = branch ? bq2 : bq1;
        unsigned* op    = branch ? q2p : q1p;
        float4 bv = *(const float4*)&bq[co0 + quad * 4];
        float bb[4] = {bv.x, bv.y, bv.z, bv.w};
        __syncthreads();   // previous use of sbuf done
#pragma unroll
        for (int nt = 0; nt < 4; ++nt) {
#pragma unroll
            for (int reg = 0; reg < 4; ++reg)
                S[(nt * 16 + l) * AST + co0 + quad * 4 + reg] =
                    packsplit(acc[branch][nt][reg] + bb[reg]);
        }
        __syncthreads();
        for (int i = tid; i < QTOK * 32; i += 512) {
            int t = i >> 5, c4 = i & 31;
            uint4 pv = *(const uint4*)&S[t * AST + c4 * 4];
            *(uint4*)&op[(size_t)(t0 + t) * CC + c4 * 4] = pv;   // 512 B/32 lanes
        }
    }
}

// ---------------------------------------------------------------------------
// Kernel 2a (r22): attention SPATIAL phase — r16 phase-1 body verbatim,
// standalone. Split from spectral so attn drops to ~53 µs and the projection
// kernels (~53-57, never yet profiled) surface in rocprof's top-5 with full
// counters. Phases are data-independent (spatial: q2p only; spectral: q1p
// only; disjoint sums ranges), so the split is trivially safe.
// ---------------------------------------------------------------------------
#define QS2 132
#define QSS 20
#define QTP 1044
__global__ __launch_bounds__(1024, 4) void attn_spatial(
    unsigned* __restrict__ q2p, float* __restrict__ sums)
{
    __shared__ __align__(16) ushort smem[HWW * QSS + HD * QTP];  // 74.4 KB
    __shared__ float fsum[CC];
    const int tid  = threadIdx.x;
    const int lane = tid & 63;
    const int l    = lane & 15;
    const int quad = lane >> 4;
    const float k2 = SCALE2 * 1.44269504f;
    const short4v onesb = {(short)0x3F80, (short)0x3F80, (short)0x3F80, (short)0x3F80};
    if (tid < CC) fsum[tid] = 0.f;

    const int d = blockIdx.x >> 3, h = blockIdx.x & 7;
    ushort* Qs  = smem;
    ushort* QTs = smem + HWW * QSS;
    const size_t base = (size_t)d * HWW * CC + h * HD;   // dword index

    for (int i = tid; i < HWW * 4; i += 1024) {
        int row = i >> 2, q4 = i & 3;
        uint4 p = *(const uint4*)&q2p[base + (size_t)row * CC + q4 * 4];
        *(uint2*)&Qs[row * QSS + q4 * 4] = pack_hi4(p);
        QTs[(q4 * 4 + 0) * QTP + row] = (ushort)p.x;
        QTs[(q4 * 4 + 1) * QTP + row] = (ushort)p.y;
        QTs[(q4 * 4 + 2) * QTP + row] = (ushort)p.z;
        QTs[(q4 * 4 + 3) * QTP + row] = (ushort)p.w;
    }
    __syncthreads();

    const int Rw = (tid >> 6) * 64;
    short4v qf[4];
#pragma unroll
    for (int lt = 0; lt < 4; ++lt) {
        short4v raw = *(short4v*)&Qs[(Rw + lt * 16 + l) * QSS + quad * 4];
        short4v sc;
#pragma unroll
        for (int e = 0; e < 4; ++e) {
            float f = bf2f((unsigned)(ushort)raw[e]) * k2;
            sc[e] = (short)bf16rne(f);
        }
        qf[lt] = sc;
    }

    float4v acc[4], accs[4];
#pragma unroll
    for (int lt = 0; lt < 4; ++lt) {
        acc[lt]  = (float4v){0.f, 0.f, 0.f, 0.f};
        accs[lt] = (float4v){0.f, 0.f, 0.f, 0.f};
    }

#pragma unroll 2
    for (int mt = 0; mt < 64; ++mt) {
        const int m0 = mt * 16;
        short4v ka = *(short4v*)&Qs[(m0 + l) * QSS + quad * 4];
        short4v vb = *(short4v*)&QTs[l * QTP + m0 + quad * 4];   // V^T A-frag
#pragma unroll
        for (int lt = 0; lt < 4; ++lt) {
            float4v s = __builtin_amdgcn_mfma_f32_16x16x16bf16_1k(
                ka, qf[lt], (float4v){0.f, 0.f, 0.f, 0.f}, 0, 0, 0);
            unsigned u0 = __float_as_uint(__builtin_amdgcn_exp2f(s[0]));
            unsigned u1 = __float_as_uint(__builtin_amdgcn_exp2f(s[1]));
            unsigned u2 = __float_as_uint(__builtin_amdgcn_exp2f(s[2]));
            unsigned u3 = __float_as_uint(__builtin_amdgcn_exp2f(s[3]));
            short4v pf = pack_pf(u0, u1, u2, u3);
            // O^T[channel][query] += V^T · P^T ; denom via A=ones
            acc[lt]  = __builtin_amdgcn_mfma_f32_16x16x16bf16_1k(vb, pf, acc[lt], 0, 0, 0);
            accs[lt] = __builtin_amdgcn_mfma_f32_16x16x16bf16_1k(onesb, pf, accs[lt], 0, 0, 0);
        }
    }

    float vsum[4] = {0.f, 0.f, 0.f, 0.f};
#pragma unroll
    for (int lt = 0; lt < 4; ++lt) {
        float inv = 1.f / accs[lt][0];   // denom(query = Rw+lt*16+l); rows equal
        int token = Rw + lt * 16 + l;
        float v0 = acc[lt][0] * inv, v1 = acc[lt][1] * inv;
        float v2 = acc[lt][2] * inv, v3 = acc[lt][3] * inv;
        uint4 pv;
        pv.x = packsplit(v0); pv.y = packsplit(v1);
        pv.z = packsplit(v2); pv.w = packsplit(v3);
        *(uint4*)&q2p[base + (size_t)token * CC + quad * 4] = pv;
        vsum[0] += v0; vsum[1] += v1; vsum[2] += v2; vsum[3] += v3;
    }
#pragma unroll
    for (int reg = 0; reg < 4; ++reg) {
        float v = vsum[reg];
        v += __shfl_xor(v, 1); v += __shfl_xor(v, 2);
        v += __shfl_xor(v, 4); v += __shfl_xor(v, 8);
        if (l == 0) atomicAdd(&fsum[quad * 4 + reg], v);
    }
    __syncthreads();
    if (tid < HD) atomicAdd(&sums[CC + h * HD + tid], fsum[tid]);
}

// ---------------------------------------------------------------------------
// Kernel 2b (r22): attention SPECTRAL phase — r16 phase-2 body verbatim,
// standalone. Grid 128, job = blockIdx (8 hw each, 2 waves/hw). In-place on
// q1p: each block reads then rewrites only its own disjoint hw-set.
// ---------------------------------------------------------------------------
__global__ __launch_bounds__(1024, 4) void attn_spectral(
    unsigned* __restrict__ q1p, float* __restrict__ sums)
{
    __shared__ __align__(16) ushort smem[8 * 32 * QS2];  // 67.6 KB
    __shared__ float fsum[CC];
    const int tid  = threadIdx.x;
    const int lane = tid & 63;
    const int l    = lane & 15;
    const int quad = lane >> 4;
    const float k2 = SCALE2 * 1.44269504f;
    const short4v onesb = {(short)0x3F80, (short)0x3F80, (short)0x3F80, (short)0x3F80};
    if (tid < CC) fsum[tid] = 0.f;

    const int hw0 = blockIdx.x * 8;
    const int wave = tid >> 6;
    const int hwl  = wave >> 1;
    const int half = wave & 1;
    const int hw   = hw0 + hwl;
    ushort* Q = smem + hwl * (32 * QS2);
    for (int it = 0; it < 8; ++it) {
        int idx = it * 64 + lane;
        int dd = half * 16 + (idx >> 5), c4 = idx & 31;
        if (dd < 31) {
            uint4 p = *(const uint4*)&q1p[((size_t)dd * HWW + hw) * CC + c4 * 4];
            *(uint2*)&Q[dd * QS2 + c4 * 4] = pack_hi4(p);
        }
    }
    if (half) for (int i = lane; i < 128; i += 64) Q[31 * QS2 + i] = 0;
    __syncthreads();

    const int hh = half * 4;
#pragma unroll
    for (int hl = 0; hl < 4; ++hl) {
        const int hc = (hh + hl) * HD;
        short4v qf[2];
        qf[0] = *(const short4v*)&Q[l * QS2 + hc + quad * 4];
        qf[1] = *(const short4v*)&Q[(16 + l) * QS2 + hc + quad * 4];
        short4v va[2];
#pragma unroll
        for (int j = 0; j < 2; ++j)
#pragma unroll
            for (int jj = 0; jj < 4; ++jj)
                va[j][jj] = (short)Q[(j * 16 + quad * 4 + jj) * QS2 + hc + l];

        float4v o[2]   = {(float4v){0.f,0.f,0.f,0.f}, (float4v){0.f,0.f,0.f,0.f}};
        float4v osr[2] = {(float4v){0.f,0.f,0.f,0.f}, (float4v){0.f,0.f,0.f,0.f}};
#pragma unroll
        for (int j = 0; j < 2; ++j) {
#pragma unroll
            for (int i2 = 0; i2 < 2; ++i2) {
                float4v s = __builtin_amdgcn_mfma_f32_16x16x16bf16_1k(
                    qf[j], qf[i2], (float4v){0.f,0.f,0.f,0.f}, 0, 0, 0);
                unsigned u0 = __float_as_uint(__builtin_amdgcn_exp2f(s[0] * k2));
                unsigned u1 = __float_as_uint(__builtin_amdgcn_exp2f(s[1] * k2));
                unsigned u2 = __float_as_uint(__builtin_amdgcn_exp2f(s[2] * k2));
                unsigned u3 = __float_as_uint(__builtin_amdgcn_exp2f(s[3] * k2));
                if (j == 1 && quad == 3) u3 = 0;   // mask key 31
                short4v pf = pack_pf(u0, u1, u2, u3);
                o[i2]   = __builtin_amdgcn_mfma_f32_16x16x16bf16_1k(va[j], pf, o[i2], 0, 0, 0);
                osr[i2] = __builtin_amdgcn_mfma_f32_16x16x16bf16_1k(onesb, pf, osr[i2], 0, 0, 0);
            }
        }
        float vsum[4] = {0.f, 0.f, 0.f, 0.f};
#pragma unroll
        for (int i2 = 0; i2 < 2; ++i2) {
            float inv = 1.f / osr[i2][0];   // rowsum(query=i2*16+l), this lane
            int dq = i2 * 16 + l;
            if (dq < 31) {
                uint4 pv;
                float v0 = o[i2][0] * inv, v1 = o[i2][1] * inv;
                float v2 = o[i2][2] * inv, v3 = o[i2][3] * inv;
                pv.x = packsplit(v0); pv.y = packsplit(v1);
                pv.z = packsplit(v2); pv.w = packsplit(v3);
                *(uint4*)&q1p[((size_t)dq * HWW + hw) * CC + hc + quad * 4] = pv;
                vsum[0] += v0; vsum[1] += v1; vsum[2] += v2; vsum[3] += v3;
            }
        }
#pragma unroll
        for (int r = 0; r < 4; ++r) {
            float v = vsum[r];
            v += __shfl_xor(v, 1); v += __shfl_xor(v, 2);
            v += __shfl_xor(v, 4); v += __shfl_xor(v, 8);
            if (l == 0) atomicAdd(&fsum[hc + quad * 4 + r], v);
        }
    }
    __syncthreads();
    if (tid < CC) atomicAdd(&sums[tid], fsum[tid]);
}

// ---------------------------------------------------------------------------
// Kernel 3: output projection + in-block gate — r8 body verbatim.
// ---------------------------------------------------------------------------
__global__ __launch_bounds__(512, 4) void oproj_kernel(
    const unsigned* __restrict__ q1p, const unsigned* __restrict__ q2p,
    const float* __restrict__ Wp1, const float* __restrict__ Wp2,
    const float* __restrict__ bp1, const float* __restrict__ bp2,
    const float* __restrict__ Wg,  const float* __restrict__ bg,
    const float* __restrict__ sums, float* __restrict__ out)
{
    __shared__ ushort sbuf[2 * 64 * AST];   // 34.8 KB: act hi/lo, then out staging
    ushort* Ahi = sbuf;
    ushort* Alo = sbuf + 64 * AST;
    unsigned* S = (unsigned*)sbuf;          // 128 x 66 dwords
    __shared__ float pa[4][CC];
    __shared__ float giv[2 * CC];
    __shared__ float gf[CC];
    const int tid = threadIdx.x;
    const int t0  = blockIdx.x * 64;
    const int lane = tid & 63;
    const int l    = lane & 15;
    const int quad = lane >> 4;
    const int co0  = (tid >> 6) * 16;

    // ---- gate phase (two-stage GEMV from sums; exact reference math) ----
    {
        const int part = tid >> 7, c = tid & 127;
        const float* Wp = (part < 2) ? Wp1 : Wp2;
        const float* sp = (part < 2) ? sums : sums + CC;
        const int k0 = (part & 1) * 64;
        float a = 0.f;
        for (int kk = 0; kk < 64; ++kk) {
            int k = k0 + kk;
            a += sp[k] * Wp[(size_t)k * CC + c];
        }
        pa[part][c] = a;
        __syncthreads();
        if (tid < 2 * CC) {
            float m = (tid < CC) ? (pa[0][tid] + pa[1][tid])
                                 : (pa[2][tid - CC] + pa[3][tid - CC]);
            float bb = (tid < CC) ? bp1[tid] : bp2[tid - CC];
            giv[tid] = m * (1.f / (float)TOK) + bb;
        }
        __syncthreads();
        float b = 0.f;
        for (int kk = 0; kk < 64; ++kk) {
            int j = part * 64 + kk;
            b += giv[j] * Wg[(size_t)j * CC + c];
        }
        pa[part][c] = b;
        __syncthreads();
        if (tid < CC)
            gf[tid] = 1.f / (1.f + __expf(-(bg[tid] + pa[0][tid] + pa[1][tid] +
                                           pa[2][tid] + pa[3][tid])));
    }

    // ---- main GEMM ----
    float4v acc[2][4];
#pragma unroll
    for (int br = 0; br < 2; ++br)
#pragma unroll
        for (int nt = 0; nt < 4; ++nt) acc[br][nt] = (float4v){0.f, 0.f, 0.f, 0.f};

    for (int br = 0; br < 2; ++br) {
        const unsigned* Ap = br ? q2p : q1p;
        const float*    W  = br ? Wp2 : Wp1;
        short8v ah[4], al[4];
        load_wfrags32(W, co0, l, quad, ah, al);
        __syncthreads();   // previous phase/branch LDS reads done
        for (int i = tid; i < 64 * 32; i += 512) {
            int t = i >> 5, c4 = i & 31;
            uint4 p = *(const uint4*)&Ap[(size_t)(t0 + t) * CC + c4 * 4];
            *(uint2*)&Ahi[t * AST + c4 * 4] = pack_hi4(p);
            *(uint2*)&Alo[t * AST + c4 * 4] = pack_lo4(p);
        }
        __syncthreads();
#pragma unroll
        for (int k4 = 0; k4 < 4; ++k4) {
#pragma unroll
            for (int nt = 0; nt < 4; ++nt) {
                short8v bh = *(const short8v*)&Ahi[(nt * 16 + l) * AST + k4 * 32 + quad * 8];
                short8v bl = *(const short8v*)&Alo[(nt * 16 + l) * AST + k4 * 32 + quad * 8];
                acc[br][nt] = mfma32(ah[k4], bh, acc[br][nt]);
                acc[br][nt] = mfma32(ah[k4], bl, acc[br][nt]);
                acc[br][nt] = mfma32(al[k4], bh, acc[br][nt]);
            }
        }
    }

    float4 b1 = *(const float4*)&bp1[co0 + quad * 4];
    float4 b2 = *(const float4*)&bp2[co0 + quad * 4];
    float bb1[4] = {b1.x, b1.y, b1.z, b1.w};
    float bb2[4] = {b2.x, b2.y, b2.z, b2.w};
    float gg[4];
#pragma unroll
    for (int e = 0; e < 4; ++e) gg[e] = gf[co0 + quad * 4 + e];

    // staged epilogue: [co][t] tile in LDS (stride 66), then contiguous stores
    __syncthreads();   // act LDS reads done
#pragma unroll
    for (int nt = 0; nt < 4; ++nt) {
        int tl = nt * 16 + l;
#pragma unroll
        for (int reg = 0; reg < 4; ++reg) {
            float v = gg[reg] * (acc[0][nt][reg] + bb1[reg]) +
                      (1.f - gg[reg]) * (acc[1][nt][reg] + bb2[reg]);
            S[(co0 + quad * 4 + reg) * 66 + tl] = __float_as_uint(v);
        }
    }
    __syncthreads();
    for (int i = tid; i < 128 * 32; i += 512) {
        int co = i >> 5, t2 = i & 31;
        uint2 v = *(const uint2*)&S[co * 66 + t2 * 2];
        *(uint2*)&out[(size_t)co * TOK + t0 + t2 * 2] = v;   // 256 B/32 lanes
    }
}

extern "C" void kernel_launch(void* const* d_in, const int* in_sizes, int n_in,
                              void* d_out, int out_size, void* d_ws, size_t ws_size,
                              hipStream_t stream)
{
    const float* x   = (const float*)d_in[0];
    const float* Wq1 = (const float*)d_in[1];
    const float* bq1 = (const float*)d_in[2];
    const float* Wp1 = (const float*)d_in[3];
    const float* bp1 = (const float*)d_in[4];
    const float* Wq2 = (const float*)d_in[5];
    const float* bq2 = (const float*)d_in[6];
    const float* Wp2 = (const float*)d_in[7];
    const float* bp2 = (const float*)d_in[8];
    const float* Wg  = (const float*)d_in[9];
    const float* bg  = (const float*)d_in[10];
    float* out = (float*)d_out;

    const size_t plane = (size_t)TOK * CC;             // dwords per packed plane
    unsigned* q1p = (unsigned*)d_ws;
    unsigned* q2p = q1p + plane;
    float*   sums = (float*)(q2p + plane);             // 256 floats (zeroed by qproj)

    const size_t need = 2 * plane * sizeof(unsigned) + 2 * CC * sizeof(float);
    if (ws_size < need) return;

    qproj_kernel<<<dim3(TOK / QTOK), 512, 0, stream>>>(x, Wq1, Wq2, bq1, bq2,
                                                       q1p, q2p, sums);
    attn_spatial<<<dim3(248), 1024, 0, stream>>>(q2p, sums);
    attn_spectral<<<dim3(128), 1024, 0, stream>>>(q1p, sums);
    oproj_kernel<<<dim3(496), 512, 0, stream>>>(q1p, q2p,
                                                Wp1, Wp2, bp1, bp2, Wg, bg,
                                                sums, out);
}

// Round 11
// 170.895 us; speedup vs baseline: 1.1214x; 1.0444x over previous
//
#include <hip/hip_runtime.h>
#include <cstddef>

#define CC 128
#define NH 8
#define HD 16
#define DDIM 31
#define HWW 1024
#define TOK 31744   // DDIM * HWW
#define SCALE2 0.0625f   // (HD^-0.5)^2 — both QK^T operands pre-scaled in the ref
#define QTOK 64     // qproj token tile (grid 496 -> 2 blocks/CU)

typedef __attribute__((ext_vector_type(4))) short  short4v;
typedef __attribute__((ext_vector_type(8))) short  short8v;
typedef __attribute__((ext_vector_type(4))) float  float4v;
typedef __attribute__((ext_vector_type(2))) unsigned uint2v;
typedef __attribute__((ext_vector_type(8))) __bf16 bf16x8;

__device__ inline unsigned bf16rne(float f) {
    unsigned u = __float_as_uint(f);
    return (u + 0x7fffu + ((u >> 16) & 1u)) >> 16;
}
__device__ inline float bf2f(unsigned h) { return __uint_as_float(h << 16); }

// Packed activation element: dword = hi_bf16 | (lo_bf16 << 16).
__device__ inline unsigned packsplit(float v) {
    unsigned h = bf16rne(v);
    unsigned l = bf16rne(v - bf2f(h));
    return h | (l << 16);
}
__device__ inline uint2 pack_hi4(uint4 p) {
    return make_uint2((p.x & 0xffffu) | (p.y << 16),
                      (p.z & 0xffffu) | (p.w << 16));
}
__device__ inline uint2 pack_lo4(uint4 p) {
    return make_uint2((p.x >> 16) | (p.y & 0xffff0000u),
                      (p.z >> 16) | (p.w & 0xffff0000u));
}

// bf16-truncate pack of 4 exp'd scores via 2x v_perm_b32 (bit-identical
// to 4x (short)(u>>16); verified r15+, absmax unchanged).
__device__ inline short4v pack_pf(unsigned u0, unsigned u1,
                                  unsigned u2, unsigned u3) {
    uint2v pd;
    pd[0] = __builtin_amdgcn_perm(u1, u0, 0x07060302u);  // [u0.hi16 | u1.hi16<<16]
    pd[1] = __builtin_amdgcn_perm(u3, u2, 0x07060302u);
    return __builtin_bit_cast(short4v, pd);
}

// Native gfx950 16x16x32 bf16 MFMA (projections, K=128). A/B built with the
// SAME per-lane k-mapping — contraction-sum-immune; C/D layout identical to
// 16x16x16 (row=quad*4+reg, col=l).
__device__ inline float4v mfma32(short8v a, short8v b, float4v c) {
    return __builtin_amdgcn_mfma_f32_16x16x32_bf16(
        __builtin_bit_cast(bf16x8, a), __builtin_bit_cast(bf16x8, b), c, 0, 0, 0);
}

// Load a wave's W^T A-frags (16 co x 128 k) from global W[k][co] as FOUR
// K=32 fragments, split to bf16 hi/lo in-register. Weights L2/L3-hot.
__device__ inline void load_wfrags32(const float* __restrict__ W, int co0, int l,
                                     int quad, short8v* ah, short8v* al)
{
#pragma unroll
    for (int k4 = 0; k4 < 4; ++k4) {
#pragma unroll
        for (int j = 0; j < 8; ++j) {
            float w = W[(size_t)(k4 * 32 + quad * 8 + j) * CC + co0 + l];
            unsigned h = bf16rne(w);
            ah[k4][j] = (short)h;
            al[k4][j] = (short)bf16rne(w - bf2f(h));
        }
    }
}

#define AST 136   // LDS act row stride (ushorts); 136 -> ds_read_b128 16B-aligned

// ---------------------------------------------------------------------------
// Kernel 1 (r23): Q projection. r8 structure, but the two branches' weight
// fragments are now loaded in SEQUENTIAL regions separated by a scheduling +
// memory barrier: peak persistent VGPR drops ~96 -> ~64 (was at the 128-cap
// spill edge; r19 proved spills here are catastrophic and counter-invisible).
// Cost: LDS B-frags read twice (+32 ds_read_b128/wave ~ 400 cyc, negligible).
// Per-acc accumulation order unchanged -> bit-identical results.
// ---------------------------------------------------------------------------
__global__ __launch_bounds__(512, 4) void qproj_kernel(
    const float* __restrict__ x,
    const float* __restrict__ Wq1, const float* __restrict__ Wq2,
    const float* __restrict__ bq1, const float* __restrict__ bq2,
    unsigned* __restrict__ q1p, unsigned* __restrict__ q2p,
    float* __restrict__ sums)
{
    __shared__ ushort sbuf[2 * QTOK * AST];   // 34.8 KB: x hi/lo, then out staging
    ushort* Ahi = sbuf;
    ushort* Alo = sbuf + QTOK * AST;
    unsigned* S = (unsigned*)sbuf;            // 64 x 136 dwords (exact fit)
    const int tid = threadIdx.x;
    const int t0  = blockIdx.x * QTOK;
    if (blockIdx.x == 0 && tid < 2 * CC) sums[tid] = 0.f;   // for attn's atomics

    // stage x tile transposed + split: [t][ci] (once, shared by both branches)
    for (int i = tid; i < QTOK * 32; i += 512) {
        int t = i & 63, c4 = i >> 6;          // lanes: consecutive t -> coalesced
        unsigned hw[2], lw[2];
#pragma unroll
        for (int p = 0; p < 2; ++p) {
            unsigned h0, l0, h1, l1;
            {
                float v = x[(size_t)(c4 * 4 + p * 2 + 0) * TOK + t0 + t];
                h0 = bf16rne(v); l0 = bf16rne(v - bf2f(h0));
            }
            {
                float v = x[(size_t)(c4 * 4 + p * 2 + 1) * TOK + t0 + t];
                h1 = bf16rne(v); l1 = bf16rne(v - bf2f(h1));
            }
            hw[p] = h0 | (h1 << 16);
            lw[p] = l0 | (l1 << 16);
        }
        *(uint2*)&Ahi[t * AST + c4 * 4] = make_uint2(hw[0], hw[1]);
        *(uint2*)&Alo[t * AST + c4 * 4] = make_uint2(lw[0], lw[1]);
    }
    __syncthreads();

    const int lane = tid & 63;
    const int l    = lane & 15;
    const int quad = lane >> 4;
    const int co0  = (tid >> 6) * 16;

    float4v acc[2][4];
#pragma unroll
    for (int br = 0; br < 2; ++br)
#pragma unroll
        for (int nt = 0; nt < 4; ++nt) acc[br][nt] = (float4v){0.f, 0.f, 0.f, 0.f};

    // ---- branch 0 GEMM (weights live only in this region) ----
    {
        short8v ah[4], al[4];
        load_wfrags32(Wq1, co0, l, quad, ah, al);
#pragma unroll
        for (int k4 = 0; k4 < 4; ++k4) {
#pragma unroll
            for (int nt = 0; nt < 4; ++nt) {
                short8v bh = *(const short8v*)&Ahi[(nt * 16 + l) * AST + k4 * 32 + quad * 8];
                short8v bl = *(const short8v*)&Alo[(nt * 16 + l) * AST + k4 * 32 + quad * 8];
                acc[0][nt] = mfma32(ah[k4], bh, acc[0][nt]);
                acc[0][nt] = mfma32(ah[k4], bl, acc[0][nt]);
                acc[0][nt] = mfma32(al[k4], bh, acc[0][nt]);
            }
        }
    }
    __builtin_amdgcn_sched_barrier(0);        // keep branch-1 loads out of
    asm volatile("" ::: "memory");            // branch-0's live range

    // ---- branch 1 GEMM ----
    {
        short8v ah[4], al[4];
        load_wfrags32(Wq2, co0, l, quad, ah, al);
#pragma unroll
        for (int k4 = 0; k4 < 4; ++k4) {
#pragma unroll
            for (int nt = 0; nt < 4; ++nt) {
                short8v bh = *(const short8v*)&Ahi[(nt * 16 + l) * AST + k4 * 32 + quad * 8];
                short8v bl = *(const short8v*)&Alo[(nt * 16 + l) * AST + k4 * 32 + quad * 8];
                acc[1][nt] = mfma32(ah[k4], bh, acc[1][nt]);
                acc[1][nt] = mfma32(ah[k4], bl, acc[1][nt]);
                acc[1][nt] = mfma32(al[k4], bh, acc[1][nt]);
            }
        }
    }

    // staged epilogues: LDS tile then contiguous full-line stores
    for (int branch = 0; branch < 2; ++branch) {
        const float* bq = branch ? bq2 : bq1;
        unsigned* op    = branch ? q2p : q1p;
        float4 bv = *(const float4*)&bq[co0 + quad * 4];
        float bb[4] = {bv.x, bv.y, bv.z, bv.w};
        __syncthreads();   // previous use of sbuf done
#pragma unroll
        for (int nt = 0; nt < 4; ++nt) {
#pragma unroll
            for (int reg = 0; reg < 4; ++reg)
                S[(nt * 16 + l) * AST + co0 + quad * 4 + reg] =
                    packsplit(acc[branch][nt][reg] + bb[reg]);
        }
        __syncthreads();
        for (int i = tid; i < QTOK * 32; i += 512) {
            int t = i >> 5, c4 = i & 31;
            uint4 pv = *(const uint4*)&S[t * AST + c4 * 4];
            *(uint4*)&op[(size_t)(t0 + t) * CC + c4 * 4] = pv;   // 512 B/32 lanes
        }
    }
}

// ---------------------------------------------------------------------------
// Kernel 2 (r23): attention, CONCURRENT phases in one launch, grid 376.
// Blocks 0..127: SPECTRAL (fast, ~8 µs, q1p only). Blocks 128..375: SPATIAL
// (~51 µs, q2p only). Phases are data-independent (disjoint planes, disjoint
// sums ranges — r10 measured split versions bit-correct). All 376 blocks are
// co-resident (75 KB LDS -> 2 blocks/CU), so spectral rides along instead of
// serializing after spatial (r16 fused = 59.4 = 50.6 spatial + ~9 serial
// spectral). Spectral-first ordering => in-order round-robin placement never
// double-books a CU with two spatial blocks. Bodies r16-verbatim.
// ---------------------------------------------------------------------------
#define QS2 132
#define QSS 20
#define QTP 1044
__global__ __launch_bounds__(1024, 4) void attn_kernel(
    unsigned* __restrict__ q1p, unsigned* __restrict__ q2p,
    float* __restrict__ sums)
{
    __shared__ __align__(16) ushort smem[HWW * QSS + HD * QTP];  // 74.4 KB
    __shared__ float fsum[CC];
    const int tid  = threadIdx.x;
    const int lane = tid & 63;
    const int l    = lane & 15;
    const int quad = lane >> 4;
    const float k2 = SCALE2 * 1.44269504f;
    const short4v onesb = {(short)0x3F80, (short)0x3F80, (short)0x3F80, (short)0x3F80};
    if (tid < CC) fsum[tid] = 0.f;

    if (blockIdx.x >= 128) {
        // ---------------- SPATIAL slice (O^T form) ----------------
        const int sp = blockIdx.x - 128;
        const int d = sp >> 3, h = sp & 7;
        ushort* Qs  = smem;
        ushort* QTs = smem + HWW * QSS;
        const size_t base = (size_t)d * HWW * CC + h * HD;   // dword index

        for (int i = tid; i < HWW * 4; i += 1024) {
            int row = i >> 2, q4 = i & 3;
            uint4 p = *(const uint4*)&q2p[base + (size_t)row * CC + q4 * 4];
            *(uint2*)&Qs[row * QSS + q4 * 4] = pack_hi4(p);
            QTs[(q4 * 4 + 0) * QTP + row] = (ushort)p.x;
            QTs[(q4 * 4 + 1) * QTP + row] = (ushort)p.y;
            QTs[(q4 * 4 + 2) * QTP + row] = (ushort)p.z;
            QTs[(q4 * 4 + 3) * QTP + row] = (ushort)p.w;
        }
        __syncthreads();

        const int Rw = (tid >> 6) * 64;
        short4v qf[4];
#pragma unroll
        for (int lt = 0; lt < 4; ++lt) {
            short4v raw = *(short4v*)&Qs[(Rw + lt * 16 + l) * QSS + quad * 4];
            short4v sc;
#pragma unroll
            for (int e = 0; e < 4; ++e) {
                float f = bf2f((unsigned)(ushort)raw[e]) * k2;
                sc[e] = (short)bf16rne(f);
            }
            qf[lt] = sc;
        }

        float4v acc[4], accs[4];
#pragma unroll
        for (int lt = 0; lt < 4; ++lt) {
            acc[lt]  = (float4v){0.f, 0.f, 0.f, 0.f};
            accs[lt] = (float4v){0.f, 0.f, 0.f, 0.f};
        }

#pragma unroll 2
        for (int mt = 0; mt < 64; ++mt) {
            const int m0 = mt * 16;
            short4v ka = *(short4v*)&Qs[(m0 + l) * QSS + quad * 4];
            short4v vb = *(short4v*)&QTs[l * QTP + m0 + quad * 4];   // V^T A-frag
#pragma unroll
            for (int lt = 0; lt < 4; ++lt) {
                float4v s = __builtin_amdgcn_mfma_f32_16x16x16bf16_1k(
                    ka, qf[lt], (float4v){0.f, 0.f, 0.f, 0.f}, 0, 0, 0);
                unsigned u0 = __float_as_uint(__builtin_amdgcn_exp2f(s[0]));
                unsigned u1 = __float_as_uint(__builtin_amdgcn_exp2f(s[1]));
                unsigned u2 = __float_as_uint(__builtin_amdgcn_exp2f(s[2]));
                unsigned u3 = __float_as_uint(__builtin_amdgcn_exp2f(s[3]));
                short4v pf = pack_pf(u0, u1, u2, u3);
                // O^T[channel][query] += V^T · P^T ; denom via A=ones
                acc[lt]  = __builtin_amdgcn_mfma_f32_16x16x16bf16_1k(vb, pf, acc[lt], 0, 0, 0);
                accs[lt] = __builtin_amdgcn_mfma_f32_16x16x16bf16_1k(onesb, pf, accs[lt], 0, 0, 0);
            }
        }

        float vsum[4] = {0.f, 0.f, 0.f, 0.f};
#pragma unroll
        for (int lt = 0; lt < 4; ++lt) {
            float inv = 1.f / accs[lt][0];   // denom(query = Rw+lt*16+l); rows equal
            int token = Rw + lt * 16 + l;
            float v0 = acc[lt][0] * inv, v1 = acc[lt][1] * inv;
            float v2 = acc[lt][2] * inv, v3 = acc[lt][3] * inv;
            uint4 pv;
            pv.x = packsplit(v0); pv.y = packsplit(v1);
            pv.z = packsplit(v2); pv.w = packsplit(v3);
            *(uint4*)&q2p[base + (size_t)token * CC + quad * 4] = pv;
            vsum[0] += v0; vsum[1] += v1; vsum[2] += v2; vsum[3] += v3;
        }
#pragma unroll
        for (int reg = 0; reg < 4; ++reg) {
            float v = vsum[reg];
            v += __shfl_xor(v, 1); v += __shfl_xor(v, 2);
            v += __shfl_xor(v, 4); v += __shfl_xor(v, 8);
            if (l == 0) atomicAdd(&fsum[quad * 4 + reg], v);
        }
        __syncthreads();
        if (tid < HD) atomicAdd(&sums[CC + h * HD + tid], fsum[tid]);
    } else {
        // ---------------- SPECTRAL job ----------------
        const int hw0 = blockIdx.x * 8;
        const int wave = tid >> 6;
        const int hwl  = wave >> 1;
        const int half = wave & 1;
        const int hw   = hw0 + hwl;
        ushort* Q = smem + hwl * (32 * QS2);
        for (int it = 0; it < 8; ++it) {
            int idx = it * 64 + lane;
            int dd = half * 16 + (idx >> 5), c4 = idx & 31;
            if (dd < 31) {
                uint4 p = *(const uint4*)&q1p[((size_t)dd * HWW + hw) * CC + c4 * 4];
                *(uint2*)&Q[dd * QS2 + c4 * 4] = pack_hi4(p);
            }
        }
        if (half) for (int i = lane; i < 128; i += 64) Q[31 * QS2 + i] = 0;
        __syncthreads();

        const int hh = half * 4;
#pragma unroll
        for (int hl = 0; hl < 4; ++hl) {
            const int hc = (hh + hl) * HD;
            short4v qf[2];
            qf[0] = *(const short4v*)&Q[l * QS2 + hc + quad * 4];
            qf[1] = *(const short4v*)&Q[(16 + l) * QS2 + hc + quad * 4];
            short4v va[2];
#pragma unroll
            for (int j = 0; j < 2; ++j)
#pragma unroll
                for (int jj = 0; jj < 4; ++jj)
                    va[j][jj] = (short)Q[(j * 16 + quad * 4 + jj) * QS2 + hc + l];

            float4v o[2]   = {(float4v){0.f,0.f,0.f,0.f}, (float4v){0.f,0.f,0.f,0.f}};
            float4v osr[2] = {(float4v){0.f,0.f,0.f,0.f}, (float4v){0.f,0.f,0.f,0.f}};
#pragma unroll
            for (int j = 0; j < 2; ++j) {
#pragma unroll
                for (int i2 = 0; i2 < 2; ++i2) {
                    float4v s = __builtin_amdgcn_mfma_f32_16x16x16bf16_1k(
                        qf[j], qf[i2], (float4v){0.f,0.f,0.f,0.f}, 0, 0, 0);
                    unsigned u0 = __float_as_uint(__builtin_amdgcn_exp2f(s[0] * k2));
                    unsigned u1 = __float_as_uint(__builtin_amdgcn_exp2f(s[1] * k2));
                    unsigned u2 = __float_as_uint(__builtin_amdgcn_exp2f(s[2] * k2));
                    unsigned u3 = __float_as_uint(__builtin_amdgcn_exp2f(s[3] * k2));
                    if (j == 1 && quad == 3) u3 = 0;   // mask key 31
                    short4v pf = pack_pf(u0, u1, u2, u3);
                    o[i2]   = __builtin_amdgcn_mfma_f32_16x16x16bf16_1k(va[j], pf, o[i2], 0, 0, 0);
                    osr[i2] = __builtin_amdgcn_mfma_f32_16x16x16bf16_1k(onesb, pf, osr[i2], 0, 0, 0);
                }
            }
            float vsum[4] = {0.f, 0.f, 0.f, 0.f};
#pragma unroll
            for (int i2 = 0; i2 < 2; ++i2) {
                float inv = 1.f / osr[i2][0];   // rowsum(query=i2*16+l), this lane
                int dq = i2 * 16 + l;
                if (dq < 31) {
                    uint4 pv;
                    float v0 = o[i2][0] * inv, v1 = o[i2][1] * inv;
                    float v2 = o[i2][2] * inv, v3 = o[i2][3] * inv;
                    pv.x = packsplit(v0); pv.y = packsplit(v1);
                    pv.z = packsplit(v2); pv.w = packsplit(v3);
                    *(uint4*)&q1p[((size_t)dq * HWW + hw) * CC + hc + quad * 4] = pv;
                    vsum[0] += v0; vsum[1] += v1; vsum[2] += v2; vsum[3] += v3;
                }
            }
#pragma unroll
            for (int r = 0; r < 4; ++r) {
                float v = vsum[r];
                v += __shfl_xor(v, 1); v += __shfl_xor(v, 2);
                v += __shfl_xor(v, 4); v += __shfl_xor(v, 8);
                if (l == 0) atomicAdd(&fsum[hc + quad * 4 + r], v);
            }
        }
        __syncthreads();
        if (tid < CC) atomicAdd(&sums[tid], fsum[tid]);
    }
}

// ---------------------------------------------------------------------------
// Kernel 3: output projection + in-block gate — r8 body verbatim.
// ---------------------------------------------------------------------------
__global__ __launch_bounds__(512, 4) void oproj_kernel(
    const unsigned* __restrict__ q1p, const unsigned* __restrict__ q2p,
    const float* __restrict__ Wp1, const float* __restrict__ Wp2,
    const float* __restrict__ bp1, const float* __restrict__ bp2,
    const float* __restrict__ Wg,  const float* __restrict__ bg,
    const float* __restrict__ sums, float* __restrict__ out)
{
    __shared__ ushort sbuf[2 * 64 * AST];   // 34.8 KB: act hi/lo, then out staging
    ushort* Ahi = sbuf;
    ushort* Alo = sbuf + 64 * AST;
    unsigned* S = (unsigned*)sbuf;          // 128 x 66 dwords
    __shared__ float pa[4][CC];
    __shared__ float giv[2 * CC];
    __shared__ float gf[CC];
    const int tid = threadIdx.x;
    const int t0  = blockIdx.x * 64;
    const int lane = tid & 63;
    const int l    = lane & 15;
    const int quad = lane >> 4;
    const int co0  = (tid >> 6) * 16;

    // ---- gate phase (two-stage GEMV from sums; exact reference math) ----
    {
        const int part = tid >> 7, c = tid & 127;
        const float* Wp = (part < 2) ? Wp1 : Wp2;
        const float* sp = (part < 2) ? sums : sums + CC;
        const int k0 = (part & 1) * 64;
        float a = 0.f;
        for (int kk = 0; kk < 64; ++kk) {
            int k = k0 + kk;
            a += sp[k] * Wp[(size_t)k * CC + c];
        }
        pa[part][c] = a;
        __syncthreads();
        if (tid < 2 * CC) {
            float m = (tid < CC) ? (pa[0][tid] + pa[1][tid])
                                 : (pa[2][tid - CC] + pa[3][tid - CC]);
            float bb = (tid < CC) ? bp1[tid] : bp2[tid - CC];
            giv[tid] = m * (1.f / (float)TOK) + bb;
        }
        __syncthreads();
        float b = 0.f;
        for (int kk = 0; kk < 64; ++kk) {
            int j = part * 64 + kk;
            b += giv[j] * Wg[(size_t)j * CC + c];
        }
        pa[part][c] = b;
        __syncthreads();
        if (tid < CC)
            gf[tid] = 1.f / (1.f + __expf(-(bg[tid] + pa[0][tid] + pa[1][tid] +
                                           pa[2][tid] + pa[3][tid])));
    }

    // ---- main GEMM ----
    float4v acc[2][4];
#pragma unroll
    for (int br = 0; br < 2; ++br)
#pragma unroll
        for (int nt = 0; nt < 4; ++nt) acc[br][nt] = (float4v){0.f, 0.f, 0.f, 0.f};

    for (int br = 0; br < 2; ++br) {
        const unsigned* Ap = br ? q2p : q1p;
        const float*    W  = br ? Wp2 : Wp1;
        short8v ah[4], al[4];
        load_wfrags32(W, co0, l, quad, ah, al);
        __syncthreads();   // previous phase/branch LDS reads done
        for (int i = tid; i < 64 * 32; i += 512) {
            int t = i >> 5, c4 = i & 31;
            uint4 p = *(const uint4*)&Ap[(size_t)(t0 + t) * CC + c4 * 4];
            *(uint2*)&Ahi[t * AST + c4 * 4] = pack_hi4(p);
            *(uint2*)&Alo[t * AST + c4 * 4] = pack_lo4(p);
        }
        __syncthreads();
#pragma unroll
        for (int k4 = 0; k4 < 4; ++k4) {
#pragma unroll
            for (int nt = 0; nt < 4; ++nt) {
                short8v bh = *(const short8v*)&Ahi[(nt * 16 + l) * AST + k4 * 32 + quad * 8];
                short8v bl = *(const short8v*)&Alo[(nt * 16 + l) * AST + k4 * 32 + quad * 8];
                acc[br][nt] = mfma32(ah[k4], bh, acc[br][nt]);
                acc[br][nt] = mfma32(ah[k4], bl, acc[br][nt]);
                acc[br][nt] = mfma32(al[k4], bh, acc[br][nt]);
            }
        }
    }

    float4 b1 = *(const float4*)&bp1[co0 + quad * 4];
    float4 b2 = *(const float4*)&bp2[co0 + quad * 4];
    float bb1[4] = {b1.x, b1.y, b1.z, b1.w};
    float bb2[4] = {b2.x, b2.y, b2.z, b2.w};
    float gg[4];
#pragma unroll
    for (int e = 0; e < 4; ++e) gg[e] = gf[co0 + quad * 4 + e];

    // staged epilogue: [co][t] tile in LDS (stride 66), then contiguous stores
    __syncthreads();   // act LDS reads done
#pragma unroll
    for (int nt = 0; nt < 4; ++nt) {
        int tl = nt * 16 + l;
#pragma unroll
        for (int reg = 0; reg < 4; ++reg) {
            float v = gg[reg] * (acc[0][nt][reg] + bb1[reg]) +
                      (1.f - gg[reg]) * (acc[1][nt][reg] + bb2[reg]);
            S[(co0 + quad * 4 + reg) * 66 + tl] = __float_as_uint(v);
        }
    }
    __syncthreads();
    for (int i = tid; i < 128 * 32; i += 512) {
        int co = i >> 5, t2 = i & 31;
        uint2 v = *(const uint2*)&S[co * 66 + t2 * 2];
        *(uint2*)&out[(size_t)co * TOK + t0 + t2 * 2] = v;   // 256 B/32 lanes
    }
}

extern "C" void kernel_launch(void* const* d_in, const int* in_sizes, int n_in,
                              void* d_out, int out_size, void* d_ws, size_t ws_size,
                              hipStream_t stream)
{
    const float* x   = (const float*)d_in[0];
    const float* Wq1 = (const float*)d_in[1];
    const float* bq1 = (const float*)d_in[2];
    const float* Wp1 = (const float*)d_in[3];
    const float* bp1 = (const float*)d_in[4];
    const float* Wq2 = (const float*)d_in[5];
    const float* bq2 = (const float*)d_in[6];
    const float* Wp2 = (const float*)d_in[7];
    const float* bp2 = (const float*)d_in[8];
    const float* Wg  = (const float*)d_in[9];
    const float* bg  = (const float*)d_in[10];
    float* out = (float*)d_out;

    const size_t plane = (size_t)TOK * CC;             // dwords per packed plane
    unsigned* q1p = (unsigned*)d_ws;
    unsigned* q2p = q1p + plane;
    float*   sums = (float*)(q2p + plane);             // 256 floats (zeroed by qproj)

    const size_t need = 2 * plane * sizeof(unsigned) + 2 * CC * sizeof(float);
    if (ws_size < need) return;

    qproj_kernel<<<dim3(TOK / QTOK), 512, 0, stream>>>(x, Wq1, Wq2, bq1, bq2,
                                                       q1p, q2p, sums);
    attn_kernel<<<dim3(376), 1024, 0, stream>>>(q1p, q2p, sums);
    oproj_kernel<<<dim3(496), 512, 0, stream>>>(q1p, q2p,
                                                Wp1, Wp2, bp1, bp2, Wg, bg,
                                                sums, out);
}

// Round 12
// 159.854 us; speedup vs baseline: 1.1988x; 1.0691x over previous
//
#include <hip/hip_runtime.h>
#include <cstddef>

#define CC 128
#define NH 8
#define HD 16
#define DDIM 31
#define HWW 1024
#define TOK 31744   // DDIM * HWW
#define SCALE2 0.0625f   // (HD^-0.5)^2 — both QK^T operands pre-scaled in the ref
#define QTOK 64     // qproj token tile (grid 496 -> 2 blocks/CU)

typedef __attribute__((ext_vector_type(4))) short  short4v;
typedef __attribute__((ext_vector_type(8))) short  short8v;
typedef __attribute__((ext_vector_type(4))) float  float4v;
typedef __attribute__((ext_vector_type(2))) unsigned uint2v;
typedef __attribute__((ext_vector_type(8))) __bf16 bf16x8;

__device__ inline unsigned bf16rne(float f) {
    unsigned u = __float_as_uint(f);
    return (u + 0x7fffu + ((u >> 16) & 1u)) >> 16;
}
__device__ inline float bf2f(unsigned h) { return __uint_as_float(h << 16); }

// Packed activation element: dword = hi_bf16 | (lo_bf16 << 16).
__device__ inline unsigned packsplit(float v) {
    unsigned h = bf16rne(v);
    unsigned l = bf16rne(v - bf2f(h));
    return h | (l << 16);
}
__device__ inline uint2 pack_hi4(uint4 p) {
    return make_uint2((p.x & 0xffffu) | (p.y << 16),
                      (p.z & 0xffffu) | (p.w << 16));
}
__device__ inline uint2 pack_lo4(uint4 p) {
    return make_uint2((p.x >> 16) | (p.y & 0xffff0000u),
                      (p.z >> 16) | (p.w & 0xffff0000u));
}

// bf16-truncate pack of 4 exp'd scores via 2x v_perm_b32 (bit-identical
// to 4x (short)(u>>16); verified r15+, absmax unchanged).
__device__ inline short4v pack_pf(unsigned u0, unsigned u1,
                                  unsigned u2, unsigned u3) {
    uint2v pd;
    pd[0] = __builtin_amdgcn_perm(u1, u0, 0x07060302u);  // [u0.hi16 | u1.hi16<<16]
    pd[1] = __builtin_amdgcn_perm(u3, u2, 0x07060302u);
    return __builtin_bit_cast(short4v, pd);
}

// Native gfx950 16x16x32 bf16 MFMA (projections, K=128). A/B built with the
// SAME per-lane k-mapping — contraction-sum-immune; C/D layout identical to
// 16x16x16 (row=quad*4+reg, col=l).
__device__ inline float4v mfma32(short8v a, short8v b, float4v c) {
    return __builtin_amdgcn_mfma_f32_16x16x32_bf16(
        __builtin_bit_cast(bf16x8, a), __builtin_bit_cast(bf16x8, b), c, 0, 0, 0);
}

// Load a wave's W^T A-frags (16 co x 128 k) from global W[k][co] as FOUR
// K=32 fragments, split to bf16 hi/lo in-register. Weights L2/L3-hot.
__device__ inline void load_wfrags32(const float* __restrict__ W, int co0, int l,
                                     int quad, short8v* ah, short8v* al)
{
#pragma unroll
    for (int k4 = 0; k4 < 4; ++k4) {
#pragma unroll
        for (int j = 0; j < 8; ++j) {
            float w = W[(size_t)(k4 * 32 + quad * 8 + j) * CC + co0 + l];
            unsigned h = bf16rne(w);
            ah[k4][j] = (short)h;
            al[k4][j] = (short)bf16rne(w - bf2f(h));
        }
    }
}

#define AST 136   // LDS act row stride (ushorts); 136 -> ds_read_b128 16B-aligned

// ---------------------------------------------------------------------------
// Kernel 1 (r24): Q projection. GEMM unchanged (r8: split hi/lo inputs for
// full-precision acc), but the OUTPUT is now a pure-bf16 half-width plane
// qh[t][c] (ushort): attn only ever consumed the hi half of the old packed
// dwords (pack_hi4 / (ushort)p.x), and attn fully overwrites q1p/q2p before
// oproj reads them — the lo output plane was 16 MB of dead writes + 16 MB of
// dead attn re-reads. Removing it is BIT-IDENTICAL end-to-end.
// Epilogue: both branches staged in one ushort LDS tile, one barrier pair.
// ---------------------------------------------------------------------------
__global__ __launch_bounds__(512, 4) void qproj_kernel(
    const float* __restrict__ x,
    const float* __restrict__ Wq1, const float* __restrict__ Wq2,
    const float* __restrict__ bq1, const float* __restrict__ bq2,
    ushort* __restrict__ qh1, ushort* __restrict__ qh2,
    float* __restrict__ sums)
{
    __shared__ ushort sbuf[2 * QTOK * AST];   // 34.8 KB: x hi/lo, then out tiles
    ushort* Ahi = sbuf;
    ushort* Alo = sbuf + QTOK * AST;
    const int tid = threadIdx.x;
    const int t0  = blockIdx.x * QTOK;
    if (blockIdx.x == 0 && tid < 2 * CC) sums[tid] = 0.f;   // for attn's atomics

    // stage x tile transposed + split: [t][ci] (once, shared by both branches)
    for (int i = tid; i < QTOK * 32; i += 512) {
        int t = i & 63, c4 = i >> 6;          // lanes: consecutive t -> coalesced
        unsigned hw[2], lw[2];
#pragma unroll
        for (int p = 0; p < 2; ++p) {
            unsigned h0, l0, h1, l1;
            {
                float v = x[(size_t)(c4 * 4 + p * 2 + 0) * TOK + t0 + t];
                h0 = bf16rne(v); l0 = bf16rne(v - bf2f(h0));
            }
            {
                float v = x[(size_t)(c4 * 4 + p * 2 + 1) * TOK + t0 + t];
                h1 = bf16rne(v); l1 = bf16rne(v - bf2f(h1));
            }
            hw[p] = h0 | (h1 << 16);
            lw[p] = l0 | (l1 << 16);
        }
        *(uint2*)&Ahi[t * AST + c4 * 4] = make_uint2(hw[0], hw[1]);
        *(uint2*)&Alo[t * AST + c4 * 4] = make_uint2(lw[0], lw[1]);
    }
    __syncthreads();

    const int lane = tid & 63;
    const int l    = lane & 15;
    const int quad = lane >> 4;
    const int co0  = (tid >> 6) * 16;

    // weight frags for BOTH branches live; one shared pass over LDS B-frags
    short8v ah[2][4], al[2][4];
    load_wfrags32(Wq1, co0, l, quad, ah[0], al[0]);
    load_wfrags32(Wq2, co0, l, quad, ah[1], al[1]);
    float4v acc[2][4];
#pragma unroll
    for (int br = 0; br < 2; ++br)
#pragma unroll
        for (int nt = 0; nt < 4; ++nt) acc[br][nt] = (float4v){0.f, 0.f, 0.f, 0.f};
#pragma unroll
    for (int k4 = 0; k4 < 4; ++k4) {
#pragma unroll
        for (int nt = 0; nt < 4; ++nt) {
            short8v bh = *(const short8v*)&Ahi[(nt * 16 + l) * AST + k4 * 32 + quad * 8];
            short8v bl = *(const short8v*)&Alo[(nt * 16 + l) * AST + k4 * 32 + quad * 8];
            acc[0][nt] = mfma32(ah[0][k4], bh, acc[0][nt]);
            acc[0][nt] = mfma32(ah[0][k4], bl, acc[0][nt]);
            acc[0][nt] = mfma32(al[0][k4], bh, acc[0][nt]);
            acc[1][nt] = mfma32(ah[1][k4], bh, acc[1][nt]);
            acc[1][nt] = mfma32(ah[1][k4], bl, acc[1][nt]);
            acc[1][nt] = mfma32(al[1][k4], bh, acc[1][nt]);
        }
    }

    // single staged epilogue: both branches' bf16 tiles, one barrier pair
    float4 bv1 = *(const float4*)&bq1[co0 + quad * 4];
    float4 bv2 = *(const float4*)&bq2[co0 + quad * 4];
    float bb[2][4] = {{bv1.x, bv1.y, bv1.z, bv1.w},
                      {bv2.x, bv2.y, bv2.z, bv2.w}};
    __syncthreads();   // GEMM's LDS reads done
#pragma unroll
    for (int br = 0; br < 2; ++br)
#pragma unroll
        for (int nt = 0; nt < 4; ++nt)
#pragma unroll
            for (int reg = 0; reg < 4; ++reg)
                sbuf[br * (QTOK * AST) + (nt * 16 + l) * AST + co0 + quad * 4 + reg] =
                    (ushort)bf16rne(acc[br][nt][reg] + bb[br][reg]);
    __syncthreads();
    for (int i = tid; i < 2 * QTOK * 16; i += 512) {   // 2048 x uint4 (8 bf16)
        int br = i >> 10, j = i & 1023;
        int t = j >> 4, c8 = j & 15;
        ushort* op = br ? qh2 : qh1;
        uint4 pv = *(const uint4*)&sbuf[br * (QTOK * AST) + t * AST + c8 * 8];
        *(uint4*)&op[(size_t)(t0 + t) * CC + c8 * 8] = pv;   // 16B/lane coalesced
    }
}

// ---------------------------------------------------------------------------
// Kernel 2 (r24): attention, CONCURRENT phases (r23 structure, grid 376;
// measured -3.4 µs vs serial-fused). Staging now reads the half-width bf16
// qh planes (uint2, no unpack) — halves attn FETCH. Outputs unchanged:
// packed hi|lo dwords into q1p/q2p for oproj.
// ---------------------------------------------------------------------------
#define QS2 132
#define QSS 20
#define QTP 1044
__global__ __launch_bounds__(1024, 4) void attn_kernel(
    const ushort* __restrict__ qh1, const ushort* __restrict__ qh2,
    unsigned* __restrict__ q1p, unsigned* __restrict__ q2p,
    float* __restrict__ sums)
{
    __shared__ __align__(16) ushort smem[HWW * QSS + HD * QTP];  // 74.4 KB
    __shared__ float fsum[CC];
    const int tid  = threadIdx.x;
    const int lane = tid & 63;
    const int l    = lane & 15;
    const int quad = lane >> 4;
    const float k2 = SCALE2 * 1.44269504f;
    const short4v onesb = {(short)0x3F80, (short)0x3F80, (short)0x3F80, (short)0x3F80};
    if (tid < CC) fsum[tid] = 0.f;

    if (blockIdx.x >= 128) {
        // ---------------- SPATIAL slice (O^T form) ----------------
        const int sp = blockIdx.x - 128;
        const int d = sp >> 3, h = sp & 7;
        ushort* Qs  = smem;
        ushort* QTs = smem + HWW * QSS;
        const size_t baseh = (size_t)d * HWW * CC + h * HD;   // ushort index
        const size_t base  = baseh;                           // dword index (out)

        for (int i = tid; i < HWW * 4; i += 1024) {
            int row = i >> 2, q4 = i & 3;
            uint2 p = *(const uint2*)&qh2[baseh + (size_t)row * CC + q4 * 4];
            *(uint2*)&Qs[row * QSS + q4 * 4] = p;
            const ushort* ps = (const ushort*)&p;
            QTs[(q4 * 4 + 0) * QTP + row] = ps[0];
            QTs[(q4 * 4 + 1) * QTP + row] = ps[1];
            QTs[(q4 * 4 + 2) * QTP + row] = ps[2];
            QTs[(q4 * 4 + 3) * QTP + row] = ps[3];
        }
        __syncthreads();

        const int Rw = (tid >> 6) * 64;
        short4v qf[4];
#pragma unroll
        for (int lt = 0; lt < 4; ++lt) {
            short4v raw = *(short4v*)&Qs[(Rw + lt * 16 + l) * QSS + quad * 4];
            short4v sc;
#pragma unroll
            for (int e = 0; e < 4; ++e) {
                float f = bf2f((unsigned)(ushort)raw[e]) * k2;
                sc[e] = (short)bf16rne(f);
            }
            qf[lt] = sc;
        }

        float4v acc[4], accs[4];
#pragma unroll
        for (int lt = 0; lt < 4; ++lt) {
            acc[lt]  = (float4v){0.f, 0.f, 0.f, 0.f};
            accs[lt] = (float4v){0.f, 0.f, 0.f, 0.f};
        }

#pragma unroll 2
        for (int mt = 0; mt < 64; ++mt) {
            const int m0 = mt * 16;
            short4v ka = *(short4v*)&Qs[(m0 + l) * QSS + quad * 4];
            short4v vb = *(short4v*)&QTs[l * QTP + m0 + quad * 4];   // V^T A-frag
#pragma unroll
            for (int lt = 0; lt < 4; ++lt) {
                float4v s = __builtin_amdgcn_mfma_f32_16x16x16bf16_1k(
                    ka, qf[lt], (float4v){0.f, 0.f, 0.f, 0.f}, 0, 0, 0);
                unsigned u0 = __float_as_uint(__builtin_amdgcn_exp2f(s[0]));
                unsigned u1 = __float_as_uint(__builtin_amdgcn_exp2f(s[1]));
                unsigned u2 = __float_as_uint(__builtin_amdgcn_exp2f(s[2]));
                unsigned u3 = __float_as_uint(__builtin_amdgcn_exp2f(s[3]));
                short4v pf = pack_pf(u0, u1, u2, u3);
                // O^T[channel][query] += V^T · P^T ; denom via A=ones
                acc[lt]  = __builtin_amdgcn_mfma_f32_16x16x16bf16_1k(vb, pf, acc[lt], 0, 0, 0);
                accs[lt] = __builtin_amdgcn_mfma_f32_16x16x16bf16_1k(onesb, pf, accs[lt], 0, 0, 0);
            }
        }

        float vsum[4] = {0.f, 0.f, 0.f, 0.f};
#pragma unroll
        for (int lt = 0; lt < 4; ++lt) {
            float inv = 1.f / accs[lt][0];   // denom(query = Rw+lt*16+l); rows equal
            int token = Rw + lt * 16 + l;
            float v0 = acc[lt][0] * inv, v1 = acc[lt][1] * inv;
            float v2 = acc[lt][2] * inv, v3 = acc[lt][3] * inv;
            uint4 pv;
            pv.x = packsplit(v0); pv.y = packsplit(v1);
            pv.z = packsplit(v2); pv.w = packsplit(v3);
            *(uint4*)&q2p[base + (size_t)token * CC + quad * 4] = pv;
            vsum[0] += v0; vsum[1] += v1; vsum[2] += v2; vsum[3] += v3;
        }
#pragma unroll
        for (int reg = 0; reg < 4; ++reg) {
            float v = vsum[reg];
            v += __shfl_xor(v, 1); v += __shfl_xor(v, 2);
            v += __shfl_xor(v, 4); v += __shfl_xor(v, 8);
            if (l == 0) atomicAdd(&fsum[quad * 4 + reg], v);
        }
        __syncthreads();
        if (tid < HD) atomicAdd(&sums[CC + h * HD + tid], fsum[tid]);
    } else {
        // ---------------- SPECTRAL job ----------------
        const int hw0 = blockIdx.x * 8;
        const int wave = tid >> 6;
        const int hwl  = wave >> 1;
        const int half = wave & 1;
        const int hw   = hw0 + hwl;
        ushort* Q = smem + hwl * (32 * QS2);
        for (int it = 0; it < 8; ++it) {
            int idx = it * 64 + lane;
            int dd = half * 16 + (idx >> 5), c4 = idx & 31;
            if (dd < 31) {
                uint2 p = *(const uint2*)&qh1[((size_t)dd * HWW + hw) * CC + c4 * 4];
                *(uint2*)&Q[dd * QS2 + c4 * 4] = p;
            }
        }
        if (half) for (int i = lane; i < 128; i += 64) Q[31 * QS2 + i] = 0;
        __syncthreads();

        const int hh = half * 4;
#pragma unroll
        for (int hl = 0; hl < 4; ++hl) {
            const int hc = (hh + hl) * HD;
            short4v qf[2];
            qf[0] = *(const short4v*)&Q[l * QS2 + hc + quad * 4];
            qf[1] = *(const short4v*)&Q[(16 + l) * QS2 + hc + quad * 4];
            short4v va[2];
#pragma unroll
            for (int j = 0; j < 2; ++j)
#pragma unroll
                for (int jj = 0; jj < 4; ++jj)
                    va[j][jj] = (short)Q[(j * 16 + quad * 4 + jj) * QS2 + hc + l];

            float4v o[2]   = {(float4v){0.f,0.f,0.f,0.f}, (float4v){0.f,0.f,0.f,0.f}};
            float4v osr[2] = {(float4v){0.f,0.f,0.f,0.f}, (float4v){0.f,0.f,0.f,0.f}};
#pragma unroll
            for (int j = 0; j < 2; ++j) {
#pragma unroll
                for (int i2 = 0; i2 < 2; ++i2) {
                    float4v s = __builtin_amdgcn_mfma_f32_16x16x16bf16_1k(
                        qf[j], qf[i2], (float4v){0.f,0.f,0.f,0.f}, 0, 0, 0);
                    unsigned u0 = __float_as_uint(__builtin_amdgcn_exp2f(s[0] * k2));
                    unsigned u1 = __float_as_uint(__builtin_amdgcn_exp2f(s[1] * k2));
                    unsigned u2 = __float_as_uint(__builtin_amdgcn_exp2f(s[2] * k2));
                    unsigned u3 = __float_as_uint(__builtin_amdgcn_exp2f(s[3] * k2));
                    if (j == 1 && quad == 3) u3 = 0;   // mask key 31
                    short4v pf = pack_pf(u0, u1, u2, u3);
                    o[i2]   = __builtin_amdgcn_mfma_f32_16x16x16bf16_1k(va[j], pf, o[i2], 0, 0, 0);
                    osr[i2] = __builtin_amdgcn_mfma_f32_16x16x16bf16_1k(onesb, pf, osr[i2], 0, 0, 0);
                }
            }
            float vsum[4] = {0.f, 0.f, 0.f, 0.f};
#pragma unroll
            for (int i2 = 0; i2 < 2; ++i2) {
                float inv = 1.f / osr[i2][0];   // rowsum(query=i2*16+l), this lane
                int dq = i2 * 16 + l;
                if (dq < 31) {
                    uint4 pv;
                    float v0 = o[i2][0] * inv, v1 = o[i2][1] * inv;
                    float v2 = o[i2][2] * inv, v3 = o[i2][3] * inv;
                    pv.x = packsplit(v0); pv.y = packsplit(v1);
                    pv.z = packsplit(v2); pv.w = packsplit(v3);
                    *(uint4*)&q1p[((size_t)dq * HWW + hw) * CC + hc + quad * 4] = pv;
                    vsum[0] += v0; vsum[1] += v1; vsum[2] += v2; vsum[3] += v3;
                }
            }
#pragma unroll
            for (int r = 0; r < 4; ++r) {
                float v = vsum[r];
                v += __shfl_xor(v, 1); v += __shfl_xor(v, 2);
                v += __shfl_xor(v, 4); v += __shfl_xor(v, 8);
                if (l == 0) atomicAdd(&fsum[hc + quad * 4 + r], v);
            }
        }
        __syncthreads();
        if (tid < CC) atomicAdd(&sums[tid], fsum[tid]);
    }
}

// ---------------------------------------------------------------------------
// Kernel 3: output projection + in-block gate — r8 body verbatim (reads the
// attn-written packed hi/lo planes; untouched by the qh change).
// ---------------------------------------------------------------------------
__global__ __launch_bounds__(512, 4) void oproj_kernel(
    const unsigned* __restrict__ q1p, const unsigned* __restrict__ q2p,
    const float* __restrict__ Wp1, const float* __restrict__ Wp2,
    const float* __restrict__ bp1, const float* __restrict__ bp2,
    const float* __restrict__ Wg,  const float* __restrict__ bg,
    const float* __restrict__ sums, float* __restrict__ out)
{
    __shared__ ushort sbuf[2 * 64 * AST];   // 34.8 KB: act hi/lo, then out staging
    ushort* Ahi = sbuf;
    ushort* Alo = sbuf + 64 * AST;
    unsigned* S = (unsigned*)sbuf;          // 128 x 66 dwords
    __shared__ float pa[4][CC];
    __shared__ float giv[2 * CC];
    __shared__ float gf[CC];
    const int tid = threadIdx.x;
    const int t0  = blockIdx.x * 64;
    const int lane = tid & 63;
    const int l    = lane & 15;
    const int quad = lane >> 4;
    const int co0  = (tid >> 6) * 16;

    // ---- gate phase (two-stage GEMV from sums; exact reference math) ----
    {
        const int part = tid >> 7, c = tid & 127;
        const float* Wp = (part < 2) ? Wp1 : Wp2;
        const float* sp = (part < 2) ? sums : sums + CC;
        const int k0 = (part & 1) * 64;
        float a = 0.f;
        for (int kk = 0; kk < 64; ++kk) {
            int k = k0 + kk;
            a += sp[k] * Wp[(size_t)k * CC + c];
        }
        pa[part][c] = a;
        __syncthreads();
        if (tid < 2 * CC) {
            float m = (tid < CC) ? (pa[0][tid] + pa[1][tid])
                                 : (pa[2][tid - CC] + pa[3][tid - CC]);
            float bb = (tid < CC) ? bp1[tid] : bp2[tid - CC];
            giv[tid] = m * (1.f / (float)TOK) + bb;
        }
        __syncthreads();
        float b = 0.f;
        for (int kk = 0; kk < 64; ++kk) {
            int j = part * 64 + kk;
            b += giv[j] * Wg[(size_t)j * CC + c];
        }
        pa[part][c] = b;
        __syncthreads();
        if (tid < CC)
            gf[tid] = 1.f / (1.f + __expf(-(bg[tid] + pa[0][tid] + pa[1][tid] +
                                           pa[2][tid] + pa[3][tid])));
    }

    // ---- main GEMM ----
    float4v acc[2][4];
#pragma unroll
    for (int br = 0; br < 2; ++br)
#pragma unroll
        for (int nt = 0; nt < 4; ++nt) acc[br][nt] = (float4v){0.f, 0.f, 0.f, 0.f};

    for (int br = 0; br < 2; ++br) {
        const unsigned* Ap = br ? q2p : q1p;
        const float*    W  = br ? Wp2 : Wp1;
        short8v ah[4], al[4];
        load_wfrags32(W, co0, l, quad, ah, al);
        __syncthreads();   // previous phase/branch LDS reads done
        for (int i = tid; i < 64 * 32; i += 512) {
            int t = i >> 5, c4 = i & 31;
            uint4 p = *(const uint4*)&Ap[(size_t)(t0 + t) * CC + c4 * 4];
            *(uint2*)&Ahi[t * AST + c4 * 4] = pack_hi4(p);
            *(uint2*)&Alo[t * AST + c4 * 4] = pack_lo4(p);
        }
        __syncthreads();
#pragma unroll
        for (int k4 = 0; k4 < 4; ++k4) {
#pragma unroll
            for (int nt = 0; nt < 4; ++nt) {
                short8v bh = *(const short8v*)&Ahi[(nt * 16 + l) * AST + k4 * 32 + quad * 8];
                short8v bl = *(const short8v*)&Alo[(nt * 16 + l) * AST + k4 * 32 + quad * 8];
                acc[br][nt] = mfma32(ah[k4], bh, acc[br][nt]);
                acc[br][nt] = mfma32(ah[k4], bl, acc[br][nt]);
                acc[br][nt] = mfma32(al[k4], bh, acc[br][nt]);
            }
        }
    }

    float4 b1 = *(const float4*)&bp1[co0 + quad * 4];
    float4 b2 = *(const float4*)&bp2[co0 + quad * 4];
    float bb1[4] = {b1.x, b1.y, b1.z, b1.w};
    float bb2[4] = {b2.x, b2.y, b2.z, b2.w};
    float gg[4];
#pragma unroll
    for (int e = 0; e < 4; ++e) gg[e] = gf[co0 + quad * 4 + e];

    // staged epilogue: [co][t] tile in LDS (stride 66), then contiguous stores
    __syncthreads();   // act LDS reads done
#pragma unroll
    for (int nt = 0; nt < 4; ++nt) {
        int tl = nt * 16 + l;
#pragma unroll
        for (int reg = 0; reg < 4; ++reg) {
            float v = gg[reg] * (acc[0][nt][reg] + bb1[reg]) +
                      (1.f - gg[reg]) * (acc[1][nt][reg] + bb2[reg]);
            S[(co0 + quad * 4 + reg) * 66 + tl] = __float_as_uint(v);
        }
    }
    __syncthreads();
    for (int i = tid; i < 128 * 32; i += 512) {
        int co = i >> 5, t2 = i & 31;
        uint2 v = *(const uint2*)&S[co * 66 + t2 * 2];
        *(uint2*)&out[(size_t)co * TOK + t0 + t2 * 2] = v;   // 256 B/32 lanes
    }
}

extern "C" void kernel_launch(void* const* d_in, const int* in_sizes, int n_in,
                              void* d_out, int out_size, void* d_ws, size_t ws_size,
                              hipStream_t stream)
{
    const float* x   = (const float*)d_in[0];
    const float* Wq1 = (const float*)d_in[1];
    const float* bq1 = (const float*)d_in[2];
    const float* Wp1 = (const float*)d_in[3];
    const float* bp1 = (const float*)d_in[4];
    const float* Wq2 = (const float*)d_in[5];
    const float* bq2 = (const float*)d_in[6];
    const float* Wp2 = (const float*)d_in[7];
    const float* bp2 = (const float*)d_in[8];
    const float* Wg  = (const float*)d_in[9];
    const float* bg  = (const float*)d_in[10];
    float* out = (float*)d_out;

    const size_t plane = (size_t)TOK * CC;             // elements per plane
    unsigned* q1p = (unsigned*)d_ws;                   // attn-out packed planes
    unsigned* q2p = q1p + plane;
    ushort*  qh1  = (ushort*)(q2p + plane);            // qproj bf16 half planes
    ushort*  qh2  = qh1 + plane;
    float*   sums = (float*)(qh2 + plane);             // 256 floats

    const size_t need = 2 * plane * sizeof(unsigned) + 2 * plane * sizeof(ushort) +
                        2 * CC * sizeof(float);
    if (ws_size < need) return;

    qproj_kernel<<<dim3(TOK / QTOK), 512, 0, stream>>>(x, Wq1, Wq2, bq1, bq2,
                                                       qh1, qh2, sums);
    attn_kernel<<<dim3(376), 1024, 0, stream>>>(qh1, qh2, q1p, q2p, sums);
    oproj_kernel<<<dim3(496), 512, 0, stream>>>(q1p, q2p,
                                                Wp1, Wp2, bp1, bp2, Wg, bg,
                                                sums, out);
}

// Round 13
// 158.008 us; speedup vs baseline: 1.2128x; 1.0117x over previous
//
#include <hip/hip_runtime.h>
#include <cstddef>

#define CC 128
#define NH 8
#define HD 16
#define DDIM 31
#define HWW 1024
#define TOK 31744   // DDIM * HWW
#define SCALE2 0.0625f   // (HD^-0.5)^2 — both QK^T operands pre-scaled in the ref
#define QTOK 64     // qproj token tile (grid 496 -> 2 blocks/CU)

typedef __attribute__((ext_vector_type(4))) short  short4v;
typedef __attribute__((ext_vector_type(8))) short  short8v;
typedef __attribute__((ext_vector_type(4))) float  float4v;
typedef __attribute__((ext_vector_type(2))) unsigned uint2v;
typedef __attribute__((ext_vector_type(8))) __bf16 bf16x8;

__device__ inline unsigned bf16rne(float f) {
    unsigned u = __float_as_uint(f);
    return (u + 0x7fffu + ((u >> 16) & 1u)) >> 16;
}
__device__ inline float bf2f(unsigned h) { return __uint_as_float(h << 16); }

// bf16-truncate pack of 4 exp'd scores via 2x v_perm_b32 (bit-identical
// to 4x (short)(u>>16); verified r15+).
__device__ inline short4v pack_pf(unsigned u0, unsigned u1,
                                  unsigned u2, unsigned u3) {
    uint2v pd;
    pd[0] = __builtin_amdgcn_perm(u1, u0, 0x07060302u);  // [u0.hi16 | u1.hi16<<16]
    pd[1] = __builtin_amdgcn_perm(u3, u2, 0x07060302u);
    return __builtin_bit_cast(short4v, pd);
}

// Native gfx950 16x16x32 bf16 MFMA (projections, K=128). A/B built with the
// SAME per-lane k-mapping — contraction-sum-immune; C/D layout identical to
// 16x16x16 (row=quad*4+reg, col=l).
__device__ inline float4v mfma32(short8v a, short8v b, float4v c) {
    return __builtin_amdgcn_mfma_f32_16x16x32_bf16(
        __builtin_bit_cast(bf16x8, a), __builtin_bit_cast(bf16x8, b), c, 0, 0, 0);
}

// Load a wave's W^T A-frags (16 co x 128 k) from global W[k][co] as FOUR
// K=32 fragments, split to bf16 hi/lo in-register. Weights L2/L3-hot.
__device__ inline void load_wfrags32(const float* __restrict__ W, int co0, int l,
                                     int quad, short8v* ah, short8v* al)
{
#pragma unroll
    for (int k4 = 0; k4 < 4; ++k4) {
#pragma unroll
        for (int j = 0; j < 8; ++j) {
            float w = W[(size_t)(k4 * 32 + quad * 8 + j) * CC + co0 + l];
            unsigned h = bf16rne(w);
            ah[k4][j] = (short)h;
            al[k4][j] = (short)bf16rne(w - bf2f(h));
        }
    }
}

#define AST 136   // LDS act row stride (ushorts); 136 -> ds_read_b128 16B-aligned

// ---------------------------------------------------------------------------
// Kernel 1: Q projection — r24 body verbatim (split hi/lo GEMM for f32-grade
// acc, single-bf16 qh output planes, one-barrier-pair dual epilogue).
// ---------------------------------------------------------------------------
__global__ __launch_bounds__(512, 4) void qproj_kernel(
    const float* __restrict__ x,
    const float* __restrict__ Wq1, const float* __restrict__ Wq2,
    const float* __restrict__ bq1, const float* __restrict__ bq2,
    ushort* __restrict__ qh1, ushort* __restrict__ qh2,
    float* __restrict__ sums)
{
    __shared__ ushort sbuf[2 * QTOK * AST];   // 34.8 KB: x hi/lo, then out tiles
    ushort* Ahi = sbuf;
    ushort* Alo = sbuf + QTOK * AST;
    const int tid = threadIdx.x;
    const int t0  = blockIdx.x * QTOK;
    if (blockIdx.x == 0 && tid < 2 * CC) sums[tid] = 0.f;   // for attn's atomics

    // stage x tile transposed + split: [t][ci] (once, shared by both branches)
    for (int i = tid; i < QTOK * 32; i += 512) {
        int t = i & 63, c4 = i >> 6;          // lanes: consecutive t -> coalesced
        unsigned hw[2], lw[2];
#pragma unroll
        for (int p = 0; p < 2; ++p) {
            unsigned h0, l0, h1, l1;
            {
                float v = x[(size_t)(c4 * 4 + p * 2 + 0) * TOK + t0 + t];
                h0 = bf16rne(v); l0 = bf16rne(v - bf2f(h0));
            }
            {
                float v = x[(size_t)(c4 * 4 + p * 2 + 1) * TOK + t0 + t];
                h1 = bf16rne(v); l1 = bf16rne(v - bf2f(h1));
            }
            hw[p] = h0 | (h1 << 16);
            lw[p] = l0 | (l1 << 16);
        }
        *(uint2*)&Ahi[t * AST + c4 * 4] = make_uint2(hw[0], hw[1]);
        *(uint2*)&Alo[t * AST + c4 * 4] = make_uint2(lw[0], lw[1]);
    }
    __syncthreads();

    const int lane = tid & 63;
    const int l    = lane & 15;
    const int quad = lane >> 4;
    const int co0  = (tid >> 6) * 16;

    // weight frags for BOTH branches live; one shared pass over LDS B-frags
    short8v ah[2][4], al[2][4];
    load_wfrags32(Wq1, co0, l, quad, ah[0], al[0]);
    load_wfrags32(Wq2, co0, l, quad, ah[1], al[1]);
    float4v acc[2][4];
#pragma unroll
    for (int br = 0; br < 2; ++br)
#pragma unroll
        for (int nt = 0; nt < 4; ++nt) acc[br][nt] = (float4v){0.f, 0.f, 0.f, 0.f};
#pragma unroll
    for (int k4 = 0; k4 < 4; ++k4) {
#pragma unroll
        for (int nt = 0; nt < 4; ++nt) {
            short8v bh = *(const short8v*)&Ahi[(nt * 16 + l) * AST + k4 * 32 + quad * 8];
            short8v bl = *(const short8v*)&Alo[(nt * 16 + l) * AST + k4 * 32 + quad * 8];
            acc[0][nt] = mfma32(ah[0][k4], bh, acc[0][nt]);
            acc[0][nt] = mfma32(ah[0][k4], bl, acc[0][nt]);
            acc[0][nt] = mfma32(al[0][k4], bh, acc[0][nt]);
            acc[1][nt] = mfma32(ah[1][k4], bh, acc[1][nt]);
            acc[1][nt] = mfma32(ah[1][k4], bl, acc[1][nt]);
            acc[1][nt] = mfma32(al[1][k4], bh, acc[1][nt]);
        }
    }

    // single staged epilogue: both branches' bf16 tiles, one barrier pair
    float4 bv1 = *(const float4*)&bq1[co0 + quad * 4];
    float4 bv2 = *(const float4*)&bq2[co0 + quad * 4];
    float bb[2][4] = {{bv1.x, bv1.y, bv1.z, bv1.w},
                      {bv2.x, bv2.y, bv2.z, bv2.w}};
    __syncthreads();   // GEMM's LDS reads done
#pragma unroll
    for (int br = 0; br < 2; ++br)
#pragma unroll
        for (int nt = 0; nt < 4; ++nt)
#pragma unroll
            for (int reg = 0; reg < 4; ++reg)
                sbuf[br * (QTOK * AST) + (nt * 16 + l) * AST + co0 + quad * 4 + reg] =
                    (ushort)bf16rne(acc[br][nt][reg] + bb[br][reg]);
    __syncthreads();
    for (int i = tid; i < 2 * QTOK * 16; i += 512) {   // 2048 x uint4 (8 bf16)
        int br = i >> 10, j = i & 1023;
        int t = j >> 4, c8 = j & 15;
        ushort* op = br ? qh2 : qh1;
        uint4 pv = *(const uint4*)&sbuf[br * (QTOK * AST) + t * AST + c8 * 8];
        *(uint4*)&op[(size_t)(t0 + t) * CC + c8 * 8] = pv;   // 16B/lane coalesced
    }
}

// ---------------------------------------------------------------------------
// Kernel 2 (r25): attention, concurrent phases (r23/r24 structure, grid 376).
// O outputs now SINGLE bf16, written IN-PLACE into the qh planes (the packed
// hi|lo q1p/q2p planes are eliminated: -16 MB write here, -16 MB read in
// oproj, at an analyzed ~2e-4 output-precision cost). In-place is safe: each
// block stages its own disjoint region fully (barrier) before overwriting it,
// and no other block touches that region (spatial: own 16-ch slice; spectral:
// own hw-columns).
// ---------------------------------------------------------------------------
#define QS2 132
#define QSS 20
#define QTP 1044
__global__ __launch_bounds__(1024, 4) void attn_kernel(
    ushort* __restrict__ qh1, ushort* __restrict__ qh2,
    float* __restrict__ sums)
{
    __shared__ __align__(16) ushort smem[HWW * QSS + HD * QTP];  // 74.4 KB
    __shared__ float fsum[CC];
    const int tid  = threadIdx.x;
    const int lane = tid & 63;
    const int l    = lane & 15;
    const int quad = lane >> 4;
    const float k2 = SCALE2 * 1.44269504f;
    const short4v onesb = {(short)0x3F80, (short)0x3F80, (short)0x3F80, (short)0x3F80};
    if (tid < CC) fsum[tid] = 0.f;

    if (blockIdx.x >= 128) {
        // ---------------- SPATIAL slice (O^T form) ----------------
        const int sp = blockIdx.x - 128;
        const int d = sp >> 3, h = sp & 7;
        ushort* Qs  = smem;
        ushort* QTs = smem + HWW * QSS;
        const size_t baseh = (size_t)d * HWW * CC + h * HD;   // ushort index

        for (int i = tid; i < HWW * 4; i += 1024) {
            int row = i >> 2, q4 = i & 3;
            uint2 p = *(const uint2*)&qh2[baseh + (size_t)row * CC + q4 * 4];
            *(uint2*)&Qs[row * QSS + q4 * 4] = p;
            const ushort* ps = (const ushort*)&p;
            QTs[(q4 * 4 + 0) * QTP + row] = ps[0];
            QTs[(q4 * 4 + 1) * QTP + row] = ps[1];
            QTs[(q4 * 4 + 2) * QTP + row] = ps[2];
            QTs[(q4 * 4 + 3) * QTP + row] = ps[3];
        }
        __syncthreads();

        const int Rw = (tid >> 6) * 64;
        short4v qf[4];
#pragma unroll
        for (int lt = 0; lt < 4; ++lt) {
            short4v raw = *(short4v*)&Qs[(Rw + lt * 16 + l) * QSS + quad * 4];
            short4v sc;
#pragma unroll
            for (int e = 0; e < 4; ++e) {
                float f = bf2f((unsigned)(ushort)raw[e]) * k2;
                sc[e] = (short)bf16rne(f);
            }
            qf[lt] = sc;
        }

        float4v acc[4], accs[4];
#pragma unroll
        for (int lt = 0; lt < 4; ++lt) {
            acc[lt]  = (float4v){0.f, 0.f, 0.f, 0.f};
            accs[lt] = (float4v){0.f, 0.f, 0.f, 0.f};
        }

#pragma unroll 2
        for (int mt = 0; mt < 64; ++mt) {
            const int m0 = mt * 16;
            short4v ka = *(short4v*)&Qs[(m0 + l) * QSS + quad * 4];
            short4v vb = *(short4v*)&QTs[l * QTP + m0 + quad * 4];   // V^T A-frag
#pragma unroll
            for (int lt = 0; lt < 4; ++lt) {
                float4v s = __builtin_amdgcn_mfma_f32_16x16x16bf16_1k(
                    ka, qf[lt], (float4v){0.f, 0.f, 0.f, 0.f}, 0, 0, 0);
                unsigned u0 = __float_as_uint(__builtin_amdgcn_exp2f(s[0]));
                unsigned u1 = __float_as_uint(__builtin_amdgcn_exp2f(s[1]));
                unsigned u2 = __float_as_uint(__builtin_amdgcn_exp2f(s[2]));
                unsigned u3 = __float_as_uint(__builtin_amdgcn_exp2f(s[3]));
                short4v pf = pack_pf(u0, u1, u2, u3);
                // O^T[channel][query] += V^T · P^T ; denom via A=ones
                acc[lt]  = __builtin_amdgcn_mfma_f32_16x16x16bf16_1k(vb, pf, acc[lt], 0, 0, 0);
                accs[lt] = __builtin_amdgcn_mfma_f32_16x16x16bf16_1k(onesb, pf, accs[lt], 0, 0, 0);
            }
        }

        float vsum[4] = {0.f, 0.f, 0.f, 0.f};
#pragma unroll
        for (int lt = 0; lt < 4; ++lt) {
            float inv = 1.f / accs[lt][0];   // denom(query = Rw+lt*16+l); rows equal
            int token = Rw + lt * 16 + l;
            float v0 = acc[lt][0] * inv, v1 = acc[lt][1] * inv;
            float v2 = acc[lt][2] * inv, v3 = acc[lt][3] * inv;
            uint2 pv;
            pv.x = bf16rne(v0) | (bf16rne(v1) << 16);
            pv.y = bf16rne(v2) | (bf16rne(v3) << 16);
            *(uint2*)&qh2[baseh + (size_t)token * CC + quad * 4] = pv;
            vsum[0] += v0; vsum[1] += v1; vsum[2] += v2; vsum[3] += v3;
        }
#pragma unroll
        for (int reg = 0; reg < 4; ++reg) {
            float v = vsum[reg];
            v += __shfl_xor(v, 1); v += __shfl_xor(v, 2);
            v += __shfl_xor(v, 4); v += __shfl_xor(v, 8);
            if (l == 0) atomicAdd(&fsum[quad * 4 + reg], v);
        }
        __syncthreads();
        if (tid < HD) atomicAdd(&sums[CC + h * HD + tid], fsum[tid]);
    } else {
        // ---------------- SPECTRAL job ----------------
        const int hw0 = blockIdx.x * 8;
        const int wave = tid >> 6;
        const int hwl  = wave >> 1;
        const int half = wave & 1;
        const int hw   = hw0 + hwl;
        ushort* Q = smem + hwl * (32 * QS2);
        for (int it = 0; it < 8; ++it) {
            int idx = it * 64 + lane;
            int dd = half * 16 + (idx >> 5), c4 = idx & 31;
            if (dd < 31) {
                uint2 p = *(const uint2*)&qh1[((size_t)dd * HWW + hw) * CC + c4 * 4];
                *(uint2*)&Q[dd * QS2 + c4 * 4] = p;
            }
        }
        if (half) for (int i = lane; i < 128; i += 64) Q[31 * QS2 + i] = 0;
        __syncthreads();

        const int hh = half * 4;
#pragma unroll
        for (int hl = 0; hl < 4; ++hl) {
            const int hc = (hh + hl) * HD;
            short4v qf[2];
            qf[0] = *(const short4v*)&Q[l * QS2 + hc + quad * 4];
            qf[1] = *(const short4v*)&Q[(16 + l) * QS2 + hc + quad * 4];
            short4v va[2];
#pragma unroll
            for (int j = 0; j < 2; ++j)
#pragma unroll
                for (int jj = 0; jj < 4; ++jj)
                    va[j][jj] = (short)Q[(j * 16 + quad * 4 + jj) * QS2 + hc + l];

            float4v o[2]   = {(float4v){0.f,0.f,0.f,0.f}, (float4v){0.f,0.f,0.f,0.f}};
            float4v osr[2] = {(float4v){0.f,0.f,0.f,0.f}, (float4v){0.f,0.f,0.f,0.f}};
#pragma unroll
            for (int j = 0; j < 2; ++j) {
#pragma unroll
                for (int i2 = 0; i2 < 2; ++i2) {
                    float4v s = __builtin_amdgcn_mfma_f32_16x16x16bf16_1k(
                        qf[j], qf[i2], (float4v){0.f,0.f,0.f,0.f}, 0, 0, 0);
                    unsigned u0 = __float_as_uint(__builtin_amdgcn_exp2f(s[0] * k2));
                    unsigned u1 = __float_as_uint(__builtin_amdgcn_exp2f(s[1] * k2));
                    unsigned u2 = __float_as_uint(__builtin_amdgcn_exp2f(s[2] * k2));
                    unsigned u3 = __float_as_uint(__builtin_amdgcn_exp2f(s[3] * k2));
                    if (j == 1 && quad == 3) u3 = 0;   // mask key 31
                    short4v pf = pack_pf(u0, u1, u2, u3);
                    o[i2]   = __builtin_amdgcn_mfma_f32_16x16x16bf16_1k(va[j], pf, o[i2], 0, 0, 0);
                    osr[i2] = __builtin_amdgcn_mfma_f32_16x16x16bf16_1k(onesb, pf, osr[i2], 0, 0, 0);
                }
            }
            float vsum[4] = {0.f, 0.f, 0.f, 0.f};
#pragma unroll
            for (int i2 = 0; i2 < 2; ++i2) {
                float inv = 1.f / osr[i2][0];   // rowsum(query=i2*16+l), this lane
                int dq = i2 * 16 + l;
                if (dq < 31) {
                    float v0 = o[i2][0] * inv, v1 = o[i2][1] * inv;
                    float v2 = o[i2][2] * inv, v3 = o[i2][3] * inv;
                    uint2 pv;
                    pv.x = bf16rne(v0) | (bf16rne(v1) << 16);
                    pv.y = bf16rne(v2) | (bf16rne(v3) << 16);
                    *(uint2*)&qh1[((size_t)dq * HWW + hw) * CC + hc + quad * 4] = pv;
                    vsum[0] += v0; vsum[1] += v1; vsum[2] += v2; vsum[3] += v3;
                }
            }
#pragma unroll
            for (int r = 0; r < 4; ++r) {
                float v = vsum[r];
                v += __shfl_xor(v, 1); v += __shfl_xor(v, 2);
                v += __shfl_xor(v, 4); v += __shfl_xor(v, 8);
                if (l == 0) atomicAdd(&fsum[hc + quad * 4 + r], v);
            }
        }
        __syncthreads();
        if (tid < CC) atomicAdd(&sums[tid], fsum[tid]);
    }
}

// ---------------------------------------------------------------------------
// Kernel 3 (r25): output projection + in-block gate. Activations arrive as
// single bf16 (qh planes): staging is a straight uint4 copy (no unpack, half
// the LDS), and the GEMM is 2 MFMA/tile (ah*b + al*b; weights stay split).
// ---------------------------------------------------------------------------
__global__ __launch_bounds__(512, 4) void oproj_kernel(
    const ushort* __restrict__ qh1, const ushort* __restrict__ qh2,
    const float* __restrict__ Wp1, const float* __restrict__ Wp2,
    const float* __restrict__ bp1, const float* __restrict__ bp2,
    const float* __restrict__ Wg,  const float* __restrict__ bg,
    const float* __restrict__ sums, float* __restrict__ out)
{
    __shared__ ushort sbuf[2 * 64 * AST];   // 34.8 KB: act tile, then out staging
    ushort* A = sbuf;
    unsigned* S = (unsigned*)sbuf;          // 128 x 66 dwords
    __shared__ float pa[4][CC];
    __shared__ float giv[2 * CC];
    __shared__ float gf[CC];
    const int tid = threadIdx.x;
    const int t0  = blockIdx.x * 64;
    const int lane = tid & 63;
    const int l    = lane & 15;
    const int quad = lane >> 4;
    const int co0  = (tid >> 6) * 16;

    // ---- gate phase (two-stage GEMV from sums; exact reference math) ----
    {
        const int part = tid >> 7, c = tid & 127;
        const float* Wp = (part < 2) ? Wp1 : Wp2;
        const float* sp = (part < 2) ? sums : sums + CC;
        const int k0 = (part & 1) * 64;
        float a = 0.f;
        for (int kk = 0; kk < 64; ++kk) {
            int k = k0 + kk;
            a += sp[k] * Wp[(size_t)k * CC + c];
        }
        pa[part][c] = a;
        __syncthreads();
        if (tid < 2 * CC) {
            float m = (tid < CC) ? (pa[0][tid] + pa[1][tid])
                                 : (pa[2][tid - CC] + pa[3][tid - CC]);
            float bb = (tid < CC) ? bp1[tid] : bp2[tid - CC];
            giv[tid] = m * (1.f / (float)TOK) + bb;
        }
        __syncthreads();
        float b = 0.f;
        for (int kk = 0; kk < 64; ++kk) {
            int j = part * 64 + kk;
            b += giv[j] * Wg[(size_t)j * CC + c];
        }
        pa[part][c] = b;
        __syncthreads();
        if (tid < CC)
            gf[tid] = 1.f / (1.f + __expf(-(bg[tid] + pa[0][tid] + pa[1][tid] +
                                           pa[2][tid] + pa[3][tid])));
    }

    // ---- main GEMM ----
    float4v acc[2][4];
#pragma unroll
    for (int br = 0; br < 2; ++br)
#pragma unroll
        for (int nt = 0; nt < 4; ++nt) acc[br][nt] = (float4v){0.f, 0.f, 0.f, 0.f};

    for (int br = 0; br < 2; ++br) {
        const ushort* Ap = br ? qh2 : qh1;
        const float*  W  = br ? Wp2 : Wp1;
        short8v ah[4], al[4];
        load_wfrags32(W, co0, l, quad, ah, al);
        __syncthreads();   // previous phase/branch LDS reads done
        for (int i = tid; i < 64 * 16; i += 512) {
            int t = i >> 4, c8 = i & 15;
            uint4 p = *(const uint4*)&Ap[(size_t)(t0 + t) * CC + c8 * 8];
            *(uint4*)&A[t * AST + c8 * 8] = p;   // straight bf16 copy, no unpack
        }
        __syncthreads();
#pragma unroll
        for (int k4 = 0; k4 < 4; ++k4) {
#pragma unroll
            for (int nt = 0; nt < 4; ++nt) {
                short8v b = *(const short8v*)&A[(nt * 16 + l) * AST + k4 * 32 + quad * 8];
                acc[br][nt] = mfma32(ah[k4], b, acc[br][nt]);
                acc[br][nt] = mfma32(al[k4], b, acc[br][nt]);
            }
        }
    }

    float4 b1 = *(const float4*)&bp1[co0 + quad * 4];
    float4 b2 = *(const float4*)&bp2[co0 + quad * 4];
    float bb1[4] = {b1.x, b1.y, b1.z, b1.w};
    float bb2[4] = {b2.x, b2.y, b2.z, b2.w};
    float gg[4];
#pragma unroll
    for (int e = 0; e < 4; ++e) gg[e] = gf[co0 + quad * 4 + e];

    // staged epilogue: [co][t] tile in LDS (stride 66), then contiguous stores
    __syncthreads();   // act LDS reads done
#pragma unroll
    for (int nt = 0; nt < 4; ++nt) {
        int tl = nt * 16 + l;
#pragma unroll
        for (int reg = 0; reg < 4; ++reg) {
            float v = gg[reg] * (acc[0][nt][reg] + bb1[reg]) +
                      (1.f - gg[reg]) * (acc[1][nt][reg] + bb2[reg]);
            S[(co0 + quad * 4 + reg) * 66 + tl] = __float_as_uint(v);
        }
    }
    __syncthreads();
    for (int i = tid; i < 128 * 32; i += 512) {
        int co = i >> 5, t2 = i & 31;
        uint2 v = *(const uint2*)&S[co * 66 + t2 * 2];
        *(uint2*)&out[(size_t)co * TOK + t0 + t2 * 2] = v;   // 256 B/32 lanes
    }
}

extern "C" void kernel_launch(void* const* d_in, const int* in_sizes, int n_in,
                              void* d_out, int out_size, void* d_ws, size_t ws_size,
                              hipStream_t stream)
{
    const float* x   = (const float*)d_in[0];
    const float* Wq1 = (const float*)d_in[1];
    const float* bq1 = (const float*)d_in[2];
    const float* Wp1 = (const float*)d_in[3];
    const float* bp1 = (const float*)d_in[4];
    const float* Wq2 = (const float*)d_in[5];
    const float* bq2 = (const float*)d_in[6];
    const float* Wp2 = (const float*)d_in[7];
    const float* bp2 = (const float*)d_in[8];
    const float* Wg  = (const float*)d_in[9];
    const float* bg  = (const float*)d_in[10];
    float* out = (float*)d_out;

    const size_t plane = (size_t)TOK * CC;             // elements per plane
    ushort* qh1 = (ushort*)d_ws;                       // bf16 planes (in-place)
    ushort* qh2 = qh1 + plane;
    float*  sums = (float*)(qh2 + plane);              // 256 floats

    const size_t need = 2 * plane * sizeof(ushort) + 2 * CC * sizeof(float);
    if (ws_size < need) return;

    qproj_kernel<<<dim3(TOK / QTOK), 512, 0, stream>>>(x, Wq1, Wq2, bq1, bq2,
                                                       qh1, qh2, sums);
    attn_kernel<<<dim3(376), 1024, 0, stream>>>(qh1, qh2, sums);
    oproj_kernel<<<dim3(496), 512, 0, stream>>>(qh1, qh2,
                                                Wp1, Wp2, bp1, bp2, Wg, bg,
                                                sums, out);
}